// Round 1
// baseline (257.106 us; speedup 1.0000x reference)
//
#include <hip/hip_runtime.h>

typedef __bf16 bf16;
typedef __bf16 bf16x2 __attribute__((ext_vector_type(2)));
typedef __bf16 bf16x8 __attribute__((ext_vector_type(8)));
typedef float  f32x4  __attribute__((ext_vector_type(4)));

#define MFMA16(a,b,c) __builtin_amdgcn_mfma_f32_16x16x32_bf16(a,b,c,0,0,0)
// async global->LDS DMA, 16B per lane; LDS dest is wave-uniform base + lane*16
#define GLL16(g, l) __builtin_amdgcn_global_load_lds( \
    (const __attribute__((address_space(1))) unsigned char*)(g), \
    (__attribute__((address_space(3))) unsigned char*)(l), 16, 0, 0)
#define BARRIER() asm volatile("s_barrier" ::: "memory")
#define DRAIN(n)  asm volatile("s_waitcnt vmcnt(" #n ")" ::: "memory")

constexpr int SEQ   = 2048;
constexpr int NH    = 16;
constexpr int HD    = 64;
constexpr int BATCH = 4;
constexpr int DM    = 1024;          // model dim
constexpr int ROWS  = BATCH * SEQ;   // 8192
constexpr size_t TEN = (size_t)BATCH * NH * SEQ * HD;   // 8,388,608 elems per tensor

// ---------------------------------------------------------------- prep: weight transpose (z=0..3) + x convert (z=4)
__global__ __launch_bounds__(256) void k_prep(const float* __restrict__ x,
                                              const float* __restrict__ W0,
                                              const float* __restrict__ W1,
                                              const float* __restrict__ W2,
                                              const float* __restrict__ W3,
                                              bf16* __restrict__ Wt_all,
                                              bf16* __restrict__ xb) {
    __shared__ float T[64][65];
    const int z = blockIdx.z;
    const int t = threadIdx.x;
    if (z == 4) {
        // convert x (fp32 -> bf16): 256 blocks x 256 threads x 128 elems
        const int bi = blockIdx.y * 16 + blockIdx.x;
#pragma unroll
        for (int c = 0; c < 16; c++) {
            const size_t idx = (size_t)c * 524288 + ((size_t)bi * 256 + t) * 8;
            float4 f0 = *(const float4*)(x + idx);
            float4 f1 = *(const float4*)(x + idx + 4);
            bf16x8 o;
            o[0] = (bf16)f0.x; o[1] = (bf16)f0.y; o[2] = (bf16)f0.z; o[3] = (bf16)f0.w;
            o[4] = (bf16)f1.x; o[5] = (bf16)f1.y; o[6] = (bf16)f1.z; o[7] = (bf16)f1.w;
            *(bf16x8*)(xb + idx) = o;
        }
        return;
    }
    const float* W = (z == 0) ? W0 : (z == 1) ? W1 : (z == 2) ? W2 : W3;
    bf16* Wt = Wt_all + (size_t)z * DM * DM;
    const int kb = blockIdx.x, nb = blockIdx.y;
    const int rl = t >> 2, seg = t & 3;
    const float* src = W + (size_t)(kb * 64 + rl) * DM + nb * 64 + seg * 16;
#pragma unroll
    for (int j4 = 0; j4 < 4; j4++) {
        float4 f = *(const float4*)(src + j4 * 4);
        T[rl][seg * 16 + j4 * 4 + 0] = f.x;
        T[rl][seg * 16 + j4 * 4 + 1] = f.y;
        T[rl][seg * 16 + j4 * 4 + 2] = f.z;
        T[rl][seg * 16 + j4 * 4 + 3] = f.w;
    }
    __syncthreads();
    bf16* dst = Wt + (size_t)(nb * 64 + rl) * DM + kb * 64 + seg * 16;
    bf16x8 o0, o1;
#pragma unroll
    for (int j = 0; j < 8; j++) {
        o0[j] = (bf16)T[seg * 16 + j][rl];
        o1[j] = (bf16)T[seg * 16 + 8 + j][rl];
    }
    *(bf16x8*)dst = o0;
    *(bf16x8*)(dst + 8) = o1;
}

// ---------------------------------------------------------------- fused QKV GEMM: 256x256 tile, BK=64, 8-phase pipeline
// Grid (32, 12): x = M/256 tile, y = z*4 + n-tile (z = 0:q 1:k 2:v).
// 512 threads = 8 waves on a 2M x 4N wave grid; per-wave C = 128x64 = acc[8][4].
// LDS 128 KB = [buf:2][mat A/B:2][half:2] x 16KB (128 rows x 64 cols bf16).
// Swizzle: phys seg s at row r holds logical seg s^(r&7); staging pre-inverse-
// swizzles the GLOBAL source (gload_lds dest must stay linear), reads apply the
// same involution -> b128 fragment reads are conflict-free (verified: the same
// scheme measures SQ_LDS_BANK_CONFLICT=0 in the previous kernel).
// Pipeline (iter i: P1-P4 compute T(2i) from buf0; P5-P8 compute T(2i+1) from
// buf1; each phase = one C-quadrant x K=64 = 16 MFMA):
//   stages: P1: A->buf1 (T2i+1, both halves)   [A-slots freed at prev P8]
//           P2/P3: B->buf0 (T2i+2)             [B buf0 fully consumed at P1]
//           P5: A->buf0 (T2i+2, both halves)   [A buf0 fully consumed at P4]
//           P6/P7: B->buf1 (T2i+3)             [B buf1 fully consumed at P5]
//   drains: vmcnt(4) at P4 => all stages <=P1 landed (covers P5-P8 consumers);
//           vmcnt(4) at P8 => all stages <=P5 landed (covers next P1-P4).
// B-halves are read entirely (8 x ds_read_b128) at the tile's first phase and
// held in regs for 4 phases; A-halves read 4 x b128 per phase. Never vmcnt(0)
// in the main loop (T4); s_setprio around the MFMA cluster (T5).
// K accumulation order matches the old kernel exactly -> bit-identical output.
__global__ __launch_bounds__(512, 2) void k_qkv(const bf16* __restrict__ A,
                                                const bf16* __restrict__ Wt0,
                                                const float* __restrict__ b0,
                                                const float* __restrict__ b1,
                                                const float* __restrict__ b2,
                                                bf16* __restrict__ out) {
    __shared__ __align__(1024) bf16 Lds[8 * 8192];   // 128 KB
    const int t = threadIdx.x;
    const int w = t >> 6, lane = t & 63, quad = lane >> 4, l16 = lane & 15;
    const int bm  = blockIdx.x * 256;
    const int by  = blockIdx.y;
    const int z   = by >> 2;                 // which projection (q/k/v)
    const int bnl = (by & 3) * 256;          // N base within matrix z
    const bf16* Wt = Wt0 + (size_t)z * DM * DM;
    const float* bias = (z == 0) ? b0 : (z == 1) ? b1 : b2;

    // staging source bases: thread -> (row = w*8 + lane>>3 within 64-row j-block,
    // phys seg = lane&7); fetch global seg (lane&7)^(lane>>3)  [r&7 == lane>>3]
    const int srow = lane >> 3;
    const int sseg = (lane & 7) ^ srow;
    const bf16* gA = A  + (size_t)(bm  + w * 8 + srow) * DM + sseg * 8;
    const bf16* gB = Wt + (size_t)(bnl + w * 8 + srow) * DM + sseg * 8;

#define SLOT(buf, mat, half) ((((buf) * 2 + (mat)) * 2 + (half)) * 8192)
#define STG(mat, buf, half, tIdx) do { \
    const bf16* _g = ((mat) ? gB : gA) + (size_t)(half) * 128 * DM + (size_t)(tIdx) * 64; \
    bf16* _l = Lds + SLOT(buf, mat, half) + w * 512; \
    GLL16(_g, _l); \
    GLL16(_g + 64 * DM, _l + 4096); \
} while (0)

    // fragment read offsets (elements), swizzled: row*64 + ((seg ^ (row&7))<<3)
    const int s0 = quad ^ (l16 & 7);          // k-slice 0: seg = quad
    const int s1 = (4 + quad) ^ (l16 & 7);    // k-slice 1: seg = 4+quad
    const int aoff0 = l16 * 64 + (s0 << 3);
    const int aoff1 = l16 * 64 + (s1 << 3);
    const int brow  = (w & 1) * 64 + l16;     // row within this wave's B-half
    const int boff0 = brow * 64 + (s0 << 3);
    const int boff1 = brow * 64 + (s1 << 3);
    const int AB0 = SLOT(0, 0, w >> 2),       AB1 = SLOT(1, 0, w >> 2);        // wave's A-half
    const int BB0 = SLOT(0, 1, (w >> 1) & 1), BB1 = SLOT(1, 1, (w >> 1) & 1); // wave's B-half

    f32x4 zero = {0.f, 0.f, 0.f, 0.f};
    f32x4 acc[8][4];
#pragma unroll
    for (int mt = 0; mt < 8; mt++)
#pragma unroll
        for (int nt = 0; nt < 4; nt++) acc[mt][nt] = zero;
    bf16x8 bfr[4][2];

#define PHASE(ABx, BBx, P, DRAIN_STMT, ...) do { \
    if ((P) == 0) { \
        _Pragma("unroll") \
        for (int nt = 0; nt < 4; nt++) { \
            bfr[nt][0] = *(const bf16x8*)(Lds + (BBx) + nt * 1024 + boff0); \
            bfr[nt][1] = *(const bf16x8*)(Lds + (BBx) + nt * 1024 + boff1); \
        } \
    } \
    bf16x8 af[2][2]; \
    _Pragma("unroll") \
    for (int mi = 0; mi < 2; mi++) { \
        af[mi][0] = *(const bf16x8*)(Lds + (ABx) + (2 * (P) + mi) * 1024 + aoff0); \
        af[mi][1] = *(const bf16x8*)(Lds + (ABx) + (2 * (P) + mi) * 1024 + aoff1); \
    } \
    __VA_ARGS__; \
    DRAIN_STMT; \
    BARRIER(); \
    __builtin_amdgcn_s_setprio(1); \
    _Pragma("unroll") \
    for (int mi = 0; mi < 2; mi++) \
        _Pragma("unroll") \
        for (int nt = 0; nt < 4; nt++) { \
            f32x4 a = acc[2 * (P) + mi][nt]; \
            a = MFMA16(af[mi][0], bfr[nt][0], a); \
            a = MFMA16(af[mi][1], bfr[nt][1], a); \
            acc[2 * (P) + mi][nt] = a; \
        } \
    __builtin_amdgcn_s_setprio(0); \
    BARRIER(); \
} while (0)

    // prologue: T0 fully (buf0) + T1's B halves (buf1); full drain once, then never vmcnt(0)
    STG(1, 0, 0, 0); STG(1, 0, 1, 0);
    STG(0, 0, 0, 0); STG(0, 0, 1, 0);
    STG(1, 1, 0, 1); STG(1, 1, 1, 1);
    DRAIN(0);
    BARRIER();

    for (int i = 0; i < 8; i++) {
        const int tO1 = 2 * i + 1;
        const int tE  = (i < 7) ? 2 * i + 2 : 15;   // last iter: re-stage T15 (L2-hot, never consumed)
        const int tO2 = (i < 7) ? 2 * i + 3 : 15;
        PHASE(AB0, BB0, 0, , STG(0, 1, 0, tO1); STG(0, 1, 1, tO1));
        PHASE(AB0, BB0, 1, , STG(1, 0, 0, tE));
        PHASE(AB0, BB0, 2, , STG(1, 0, 1, tE));
        PHASE(AB0, BB0, 3, DRAIN(4), );
        PHASE(AB1, BB1, 0, , STG(0, 0, 0, tE); STG(0, 0, 1, tE));
        PHASE(AB1, BB1, 1, , STG(1, 1, 0, tO2));
        PHASE(AB1, BB1, 2, , STG(1, 1, 1, tO2));
        PHASE(AB1, BB1, 3, DRAIN(4), );
    }
#undef PHASE
#undef STG
#undef SLOT

    // epilogue: bias + fused RoPE (z<2) + scatter to [B,H,S,D] (+ z*TEN)
    const int wml = (w >> 2) * 128;
    const int wnl = (w & 3) * 64;
    float bv[4], invf[4];
#pragma unroll
    for (int nt = 0; nt < 4; nt++) {
        const int colz = bnl + wnl + nt * 16 + l16;
        bv[nt] = bias[colz];
        const int ip = (colz & 63) >> 1;
        invf[nt] = __builtin_exp2f(-0.41524101186092029f * (float)ip);
    }
    const int odd = l16 & 1;
#pragma unroll
    for (int mt = 0; mt < 8; mt++) {
#pragma unroll
        for (int nt = 0; nt < 4; nt++) {
            const int colz = bnl + wnl + nt * 16 + l16;
            const int h = colz >> 6, dd = colz & 63;
#pragma unroll
            for (int rg = 0; rg < 4; rg++) {
                const int row = bm + wml + mt * 16 + quad * 4 + rg;
                float val = acc[mt][nt][rg] + bv[nt];
                const int b = row >> 11, s = row & (SEQ - 1);
                if (z < 2) {   // fused RoPE on q,k (q also pre-scaled by 1/8)
                    const float partner = __shfl_xor(val, 1);
                    float sn, cs;
                    __sincosf((float)s * invf[nt], &sn, &cs);
                    val = odd ? (val * cs + partner * sn)
                              : (val * cs - partner * sn);
                    if (z == 0) val *= 0.125f;
                }
                out[(size_t)z * TEN +
                    (((size_t)(b * NH + h)) * SEQ + s) * HD + dd] = (bf16)val;
            }
        }
    }
}

// ---------------------------------------------------------------- GEMM (m97 structure) — used for the output projection
// 128x128 tile, BK=32, global_load_lds(16B) staging, XOR-swizzled LDS.
// MODE 1: out fp32 [row][col].
template <int MODE>
__global__ __launch_bounds__(256) void k_gemm(const bf16* __restrict__ A,
                                              const bf16* __restrict__ Wt0,
                                              const float* __restrict__ b0,
                                              const float* __restrict__ b1,
                                              const float* __restrict__ b2,
                                              void* __restrict__ out) {
    __shared__ __align__(1024) bf16 AsF[128 * 32];   // 8 KB, swizzled
    __shared__ __align__(1024) bf16 BsF[128 * 32];   // 8 KB, swizzled
    const int z = blockIdx.z;
    const bf16* Wt = Wt0 + (size_t)z * DM * DM;
    const float* bias = (z == 0) ? b0 : (z == 1) ? b1 : b2;

    const int t = threadIdx.x;
    const int w = t >> 6, lane = t & 63, quad = lane >> 4, l16 = lane & 15;
    const int bm = blockIdx.x * 128, bn = blockIdx.y * 128;
    const int wm = (w >> 1) * 64, wn = (w & 1) * 64;

    const int c0 = w * 2, c1 = w * 2 + 1;
    const int sg0 = c0 * 64 + lane, sg1 = c1 * 64 + lane;
    const int r0 = sg0 >> 2, r1 = sg1 >> 2;
    const int csg0 = (sg0 & 3) ^ ((r0 >> 1) & 3);
    const int csg1 = (sg1 & 3) ^ ((r1 >> 1) & 3);
    const bf16* gA0 = A  + (size_t)(bm + r0) * DM + csg0 * 8;
    const bf16* gA1 = A  + (size_t)(bm + r1) * DM + csg1 * 8;
    const bf16* gB0 = Wt + (size_t)(bn + r0) * DM + csg0 * 8;
    const bf16* gB1 = Wt + (size_t)(bn + r1) * DM + csg1 * 8;
    bf16* lA0 = AsF + c0 * 512;
    bf16* lA1 = AsF + c1 * 512;
    bf16* lB0 = BsF + c0 * 512;
    bf16* lB1 = BsF + c1 * 512;

    const bf16* pA[4]; const bf16* pB[4];
#pragma unroll
    for (int mt = 0; mt < 4; mt++) {
        const int r = wm + mt * 16 + l16;
        pA[mt] = AsF + r * 32 + ((quad ^ ((r >> 1) & 3)) << 3);
    }
#pragma unroll
    for (int nt = 0; nt < 4; nt++) {
        const int r = wn + nt * 16 + l16;
        pB[nt] = BsF + r * 32 + ((quad ^ ((r >> 1) & 3)) << 3);
    }

    f32x4 zero = {0.f, 0.f, 0.f, 0.f};
    f32x4 acc[4][4];
#pragma unroll
    for (int mt = 0; mt < 4; mt++)
#pragma unroll
        for (int nt = 0; nt < 4; nt++) acc[mt][nt] = zero;

    for (int k0 = 0; k0 < DM; k0 += 32) {
        __syncthreads();
        GLL16(gA0, lA0);
        GLL16(gA1, lA1);
        GLL16(gB0, lB0);
        GLL16(gB1, lB1);
        gA0 += 32; gA1 += 32; gB0 += 32; gB1 += 32;
        __syncthreads();

        bf16x8 af[4], bfr[4];
#pragma unroll
        for (int mt = 0; mt < 4; mt++) af[mt]  = *(const bf16x8*)pA[mt];
#pragma unroll
        for (int nt = 0; nt < 4; nt++) bfr[nt] = *(const bf16x8*)pB[nt];
#pragma unroll
        for (int mt = 0; mt < 4; mt++)
#pragma unroll
            for (int nt = 0; nt < 4; nt++)
                acc[mt][nt] = MFMA16(af[mt], bfr[nt], acc[mt][nt]);
    }

    float bv[4];
#pragma unroll
    for (int nt = 0; nt < 4; nt++) {
        const int col = bn + wn + nt * 16 + l16;
        bv[nt] = bias[col];
    }

#pragma unroll
    for (int mt = 0; mt < 4; mt++) {
#pragma unroll
        for (int nt = 0; nt < 4; nt++) {
            const int col = bn + wn + nt * 16 + l16;
#pragma unroll
            for (int rg = 0; rg < 4; rg++) {
                const int row = bm + wm + mt * 16 + quad * 4 + rg;
                float val = acc[mt][nt][rg] + bv[nt];
                ((float*)out)[(size_t)row * DM + col] = val;
            }
        }
    }
}

// ---------------------------------------------------------------- V transpose: [B,H,S,D] -> [B,H,D,S]
__global__ __launch_bounds__(256) void k_vtrans(const bf16* __restrict__ v, bf16* __restrict__ vt) {
    __shared__ float T[64][65];
    const int t = threadIdx.x;
    const int sb = blockIdx.x, bh = blockIdx.y;
    const int rl = t >> 2, seg = t & 3;
    const bf16* src = v + ((size_t)bh * SEQ + sb * 64 + rl) * HD + seg * 16;
    bf16x8 i0 = *(const bf16x8*)src;
    bf16x8 i1 = *(const bf16x8*)(src + 8);
#pragma unroll
    for (int j = 0; j < 8; j++) {
        T[rl][seg * 16 + j]     = (float)i0[j];
        T[rl][seg * 16 + 8 + j] = (float)i1[j];
    }
    __syncthreads();
    bf16* dst = vt + ((size_t)bh * HD + rl) * SEQ + sb * 64 + seg * 16;
    bf16x8 o0, o1;
#pragma unroll
    for (int j = 0; j < 8; j++) {
        o0[j] = (bf16)T[seg * 16 + j][rl];
        o1[j] = (bf16)T[seg * 16 + 8 + j][rl];
    }
    *(bf16x8*)dst = o0;
    *(bf16x8*)(dst + 8) = o1;
}

// ---------------------------------------------------------------- flash attention (causal)
// grid: (bh=64, 16). qb = 15 - blockIdx.y (heavy-first). One 128-row q-block per block.
// __launch_bounds__(256,2): (256,4) made the allocator target 64 VGPRs -> spilled
// accumulators to scratch. Wave w owns rows w*32..w*32+31 (2 m-tiles). K/V/P in
// unpadded XOR-swizzled LDS (seg' = seg ^ (row&7)); staging via global_load_lds.
// Softmax: fixed offset -10 in acc init; row-sum deferred to epilogue; P transpose via
// wave-private swizzled LDS (no barrier). Wave-level skip of fully-masked corner.
__global__ __launch_bounds__(256, 2) void k_attn(const bf16* __restrict__ q,
                                                 const bf16* __restrict__ k,
                                                 const bf16* __restrict__ vt,
                                                 bf16* __restrict__ y) {
    __shared__ __align__(1024) bf16 KsF[64 * 64];      // 8 KB [kv][d] swizzled
    __shared__ __align__(1024) bf16 VsF[64 * 64];      // 8 KB [d][kv] swizzled
    __shared__ __align__(1024) bf16 PsF[4 * 32 * 64];  // 16 KB per-wave P scratch, swizzled
    const int t = threadIdx.x;
    const int w = t >> 6, lane = t & 63, quad = lane >> 4, l16 = lane & 15;
    const int bh = blockIdx.x;
    const int qb = 15 - (int)blockIdx.y;
    const int b = bh >> 4, h = bh & 15;

    const int srow = lane >> 3;
    const int gseg = (lane & 7) ^ srow;
    const int c0 = w, c1 = w + 4;

    const bf16* kbase = k  + (size_t)bh * SEQ * HD;
    const bf16* vbase = vt + (size_t)bh * HD * SEQ;
    const float NEG_INF = -__builtin_inff();

    const bf16 *kf_p[4][2], *vf_p[4][2], *pf_p[2][2];
#pragma unroll
    for (int nt = 0; nt < 4; nt++) {
        const int r = nt * 16 + l16;
#pragma unroll
        for (int hh = 0; hh < 2; hh++) {
            const int sg = hh * 4 + quad;
            kf_p[nt][hh] = KsF + r * 64 + (((sg ^ (r & 7))) << 3);
            vf_p[nt][hh] = VsF + r * 64 + (((sg ^ (r & 7))) << 3);
        }
    }
#pragma unroll
    for (int mt = 0; mt < 2; mt++) {
        const int r = mt * 16 + l16;
#pragma unroll
        for (int hh = 0; hh < 2; hh++) {
            const int sg = hh * 4 + quad;
            pf_p[mt][hh] = PsF + w * 2048 + r * 64 + (((sg ^ (r & 7))) << 3);
        }
    }

    bf16x8 qf[2][2];
#pragma unroll
    for (int mt = 0; mt < 2; mt++) {
        const bf16* qrow = q + ((size_t)bh * SEQ + qb * 128 + w * 32 + mt * 16 + l16) * HD;
        qf[mt][0] = *(const bf16x8*)(qrow + quad * 8);
        qf[mt][1] = *(const bf16x8*)(qrow + 32 + quad * 8);
    }

    f32x4 zero = {0.f, 0.f, 0.f, 0.f};
    f32x4 minus10 = {-10.f, -10.f, -10.f, -10.f};
    f32x4 acc_o[2][4];
    float l_acc[2][4];
#pragma unroll
    for (int mt = 0; mt < 2; mt++)
#pragma unroll
        for (int nt = 0; nt < 4; nt++) acc_o[mt][nt] = zero;
#pragma unroll
    for (int mt = 0; mt < 2; mt++)
#pragma unroll
        for (int rg = 0; rg < 4; rg++) l_acc[mt][rg] = 0.f;

    const bf16* kg0 = kbase + (size_t)(c0 * 8 + srow) * HD + gseg * 8;
    const bf16* kg1 = kbase + (size_t)(c1 * 8 + srow) * HD + gseg * 8;
    const bf16* vg0 = vbase + (size_t)(c0 * 8 + srow) * SEQ + gseg * 8;
    const bf16* vg1 = vbase + (size_t)(c1 * 8 + srow) * SEQ + gseg * 8;
    const int ktmax = 2 * qb + 1;

    for (int kt = 0; kt <= ktmax; kt++) {
        __syncthreads();
        GLL16(kg0, KsF + c0 * 512);
        GLL16(kg1, KsF + c1 * 512);
        GLL16(vg0, VsF + c0 * 512);
        GLL16(vg1, VsF + c1 * 512);
        kg0 += 64 * HD; kg1 += 64 * HD; vg0 += 64; vg1 += 64;
        __syncthreads();

        const int d = qb * 128 + w * 32 - kt * 64;
        if (d > -32) {
            // ---- S = Q K^T - 10
            f32x4 accs[2][4];
#pragma unroll
            for (int nt = 0; nt < 4; nt++) {
                const bf16x8 kf0 = *(const bf16x8*)kf_p[nt][0];
                const bf16x8 kf1 = *(const bf16x8*)kf_p[nt][1];
#pragma unroll
                for (int mt = 0; mt < 2; mt++) {
                    f32x4 a = minus10;
                    a = MFMA16(qf[mt][0], kf0, a);
                    a = MFMA16(qf[mt][1], kf1, a);
                    accs[mt][nt] = a;
                }
            }
            // ---- causal mask
            if (d < 64) {
#pragma unroll
                for (int mt = 0; mt < 2; mt++) {
                    const int qr = d + mt * 16 + quad * 4;
#pragma unroll
                    for (int nt = 0; nt < 4; nt++) {
                        const int kv = nt * 16 + l16;
#pragma unroll
                        for (int rg = 0; rg < 4; rg++)
                            if (kv > qr + rg) accs[mt][nt][rg] = NEG_INF;
                    }
                }
            }
            // ---- p = exp(S-10); per-lane row-sum; P -> swizzled wave-private LDS
#pragma unroll
            for (int mt = 0; mt < 2; mt++) {
#pragma unroll
                for (int nt = 0; nt < 4; nt++) {
#pragma unroll
                    for (int rg = 0; rg < 4; rg++) {
                        const float p = __expf(accs[mt][nt][rg]);
                        l_acc[mt][rg] += p;
                        const int prow = mt * 16 + quad * 4 + rg;
                        const int psg  = (nt * 2 + (l16 >> 3)) ^ (prow & 7);
                        PsF[w * 2048 + prow * 64 + psg * 8 + (l16 & 7)] = (bf16)p;
                    }
                }
            }
            // ---- O += P V
            bf16x8 pf[2][2];
#pragma unroll
            for (int mt = 0; mt < 2; mt++) {
                pf[mt][0] = *(const bf16x8*)pf_p[mt][0];
                pf[mt][1] = *(const bf16x8*)pf_p[mt][1];
            }
#pragma unroll
            for (int nt = 0; nt < 4; nt++) {
                const bf16x8 vf0 = *(const bf16x8*)vf_p[nt][0];
                const bf16x8 vf1 = *(const bf16x8*)vf_p[nt][1];
#pragma unroll
                for (int mt = 0; mt < 2; mt++) {
                    acc_o[mt][nt] = MFMA16(pf[mt][0], vf0, acc_o[mt][nt]);
                    acc_o[mt][nt] = MFMA16(pf[mt][1], vf1, acc_o[mt][nt]);
                }
            }
        }
    }

    // ---- epilogue
#pragma unroll
    for (int mt = 0; mt < 2; mt++) {
#pragma unroll
        for (int rg = 0; rg < 4; rg++) {
            float rs = l_acc[mt][rg];
            rs += __shfl_xor(rs, 1);
            rs += __shfl_xor(rs, 2);
            rs += __shfl_xor(rs, 4);
            rs += __shfl_xor(rs, 8);
            const float inv = 1.0f / rs;
            const int s = qb * 128 + w * 32 + mt * 16 + quad * 4 + rg;
#pragma unroll
            for (int nt = 0; nt < 4; nt++) {
                const float val = acc_o[mt][nt][rg] * inv;
                y[((size_t)(b * SEQ + s)) * DM + h * HD + nt * 16 + l16] = (bf16)val;
            }
        }
    }
}

// ---------------------------------------------------------------- launch
extern "C" void kernel_launch(void* const* d_in, const int* in_sizes, int n_in,
                              void* d_out, int out_size, void* d_ws, size_t ws_size,
                              hipStream_t stream) {
    const float* x  = (const float*)d_in[0];
    const float* Wq = (const float*)d_in[1];
    const float* bq = (const float*)d_in[2];
    const float* Wk = (const float*)d_in[3];
    const float* bk = (const float*)d_in[4];
    const float* Wv = (const float*)d_in[5];
    const float* bv = (const float*)d_in[6];
    const float* Wo = (const float*)d_in[7];
    const float* bo = (const float*)d_in[8];

    // Workspace layout (88 MB total).
    char* ws = (char*)d_ws;
    bf16* xb   = (bf16*)(ws);                       // 16 MB: x bf16; reused as attn out y
    bf16* wall = (bf16*)(ws + (16ull << 20));       //  8 MB: Wq^T,Wk^T,Wv^T,Wo^T bf16
    bf16* qb   = (bf16*)(ws + (24ull << 20));       // 16 MB (q,k,v contiguous: +z*TEN)
    bf16* kb   = (bf16*)(ws + (40ull << 20));       // 16 MB
    bf16* vb   = (bf16*)(ws + (56ull << 20));       // 16 MB
    bf16* vtb  = (bf16*)(ws + (72ull << 20));       // 16 MB: V^T [B,H,D,S]
    bf16* wot  = wall + 3ull * DM * DM;

    k_prep<<<dim3(16, 16, 5), 256, 0, stream>>>(x, Wq, Wk, Wv, Wo, wall, xb);
    k_qkv<<<dim3(32, 12), 512, 0, stream>>>(xb, wall, bq, bk, bv, qb);
    k_vtrans<<<dim3(32, 64), 256, 0, stream>>>(vb, vtb);
    k_attn<<<dim3(64, 16), 256, 0, stream>>>(qb, kb, vtb, xb);
    k_gemm<1><<<dim3(64, 8, 1), 256, 0, stream>>>(xb, wot, bo, bo, bo, d_out);
}

// Round 2
// 253.731 us; speedup vs baseline: 1.0133x; 1.0133x over previous
//
#include <hip/hip_runtime.h>

typedef __bf16 bf16;
typedef __bf16 bf16x2 __attribute__((ext_vector_type(2)));
typedef __bf16 bf16x4 __attribute__((ext_vector_type(4)));
typedef __bf16 bf16x8 __attribute__((ext_vector_type(8)));
typedef float  f32x4  __attribute__((ext_vector_type(4)));

#define MFMA16(a,b,c) __builtin_amdgcn_mfma_f32_16x16x32_bf16(a,b,c,0,0,0)
// async global->LDS DMA, 16B per lane; LDS dest is wave-uniform base + lane*16
#define GLL16(g, l) __builtin_amdgcn_global_load_lds( \
    (const __attribute__((address_space(1))) unsigned char*)(g), \
    (__attribute__((address_space(3))) unsigned char*)(l), 16, 0, 0)
#define BARRIER() asm volatile("s_barrier" ::: "memory")
#define DRAIN(n)  asm volatile("s_waitcnt vmcnt(" #n ")" ::: "memory")

constexpr int SEQ   = 2048;
constexpr int NH    = 16;
constexpr int HD    = 64;
constexpr int BATCH = 4;
constexpr int DM    = 1024;          // model dim
constexpr int ROWS  = BATCH * SEQ;   // 8192
constexpr size_t TEN = (size_t)BATCH * NH * SEQ * HD;   // 8,388,608 elems per tensor

// ---------------------------------------------------------------- prep: weight transpose (z=0..3) + x convert (z=4)
__global__ __launch_bounds__(256) void k_prep(const float* __restrict__ x,
                                              const float* __restrict__ W0,
                                              const float* __restrict__ W1,
                                              const float* __restrict__ W2,
                                              const float* __restrict__ W3,
                                              bf16* __restrict__ Wt_all,
                                              bf16* __restrict__ xb) {
    __shared__ float T[64][65];
    const int z = blockIdx.z;
    const int t = threadIdx.x;
    if (z == 4) {
        // convert x (fp32 -> bf16): 256 blocks x 256 threads x 128 elems
        const int bi = blockIdx.y * 16 + blockIdx.x;
#pragma unroll
        for (int c = 0; c < 16; c++) {
            const size_t idx = (size_t)c * 524288 + ((size_t)bi * 256 + t) * 8;
            float4 f0 = *(const float4*)(x + idx);
            float4 f1 = *(const float4*)(x + idx + 4);
            bf16x8 o;
            o[0] = (bf16)f0.x; o[1] = (bf16)f0.y; o[2] = (bf16)f0.z; o[3] = (bf16)f0.w;
            o[4] = (bf16)f1.x; o[5] = (bf16)f1.y; o[6] = (bf16)f1.z; o[7] = (bf16)f1.w;
            *(bf16x8*)(xb + idx) = o;
        }
        return;
    }
    const float* W = (z == 0) ? W0 : (z == 1) ? W1 : (z == 2) ? W2 : W3;
    bf16* Wt = Wt_all + (size_t)z * DM * DM;
    const int kb = blockIdx.x, nb = blockIdx.y;
    const int rl = t >> 2, seg = t & 3;
    const float* src = W + (size_t)(kb * 64 + rl) * DM + nb * 64 + seg * 16;
#pragma unroll
    for (int j4 = 0; j4 < 4; j4++) {
        float4 f = *(const float4*)(src + j4 * 4);
        T[rl][seg * 16 + j4 * 4 + 0] = f.x;
        T[rl][seg * 16 + j4 * 4 + 1] = f.y;
        T[rl][seg * 16 + j4 * 4 + 2] = f.z;
        T[rl][seg * 16 + j4 * 4 + 3] = f.w;
    }
    __syncthreads();
    bf16* dst = Wt + (size_t)(nb * 64 + rl) * DM + kb * 64 + seg * 16;
    bf16x8 o0, o1;
#pragma unroll
    for (int j = 0; j < 8; j++) {
        o0[j] = (bf16)T[seg * 16 + j][rl];
        o1[j] = (bf16)T[seg * 16 + 8 + j][rl];
    }
    *(bf16x8*)dst = o0;
    *(bf16x8*)(dst + 8) = o1;
}

// ---------------------------------------------------------------- GEMM: 128x128 tile, BK=32, depth-2 prefetch pipeline
// Keeps the round-0 co-resident geometry (grid 1536/512, 4 waves, 48KB LDS ->
// 3 blocks/CU) and replaces the serial stage->vmcnt(0)->compute step with a
// 3-buffer rotation: iter t computes buf[t%3] while staging tile t+2 into
// buf[(t+2)%3]; one barrier per K-step; DRAIN(4) (counted, never 0) completes
// stage(t+1) while stage(t+2) stays in flight -> ~2 iters (~350cy) of load
// latency overlap per tile, filled further by 3 co-resident blocks.
// Buffer-write safety: buf[(t+2)%3] was last READ at iter t-1; the barrier at
// the end of t-1 guarantees all waves are done before any t-issued DMA lands.
// K accumulation order unchanged -> bit-identical to round-0 output.
// MODE 0: z=0 (q, RoPE+1/8 scale) / z=1 (k, RoPE) scatter to [B,H,S,D];
//         z=2 (v) stores TRANSPOSED directly to vt [B,H,D,S] as bf16x4
//         (4 consecutive s per lane) — eliminates the k_vtrans pass.
// MODE 1: out fp32 [row][col].
template <int MODE>
__global__ __launch_bounds__(256, 3) void k_gemm(const bf16* __restrict__ A,
                                                 const bf16* __restrict__ Wt0,
                                                 const float* __restrict__ b0,
                                                 const float* __restrict__ b1,
                                                 const float* __restrict__ b2,
                                                 bf16* __restrict__ vt,
                                                 void* __restrict__ out) {
    __shared__ __align__(1024) bf16 AsF[3][4096];   // 3 x 8 KB, swizzled
    __shared__ __align__(1024) bf16 BsF[3][4096];   // 3 x 8 KB, swizzled
    const int z = blockIdx.z;
    const bf16* Wt = Wt0 + (size_t)z * DM * DM;
    const float* bias = (z == 0) ? b0 : (z == 1) ? b1 : b2;

    const int t = threadIdx.x;
    const int w = t >> 6, lane = t & 63, quad = lane >> 4, l16 = lane & 15;
    const int bm = blockIdx.x * 128, bn = blockIdx.y * 128;   // x = M: A-sharers
    const int wm = (w >> 1) * 64, wn = (w & 1) * 64;

    // staging: 8 chunks of 1024B per 8KB tile; wave w DMAs chunks w*2, w*2+1
    const int c0 = w * 2, c1 = w * 2 + 1;
    const int sg0 = c0 * 64 + lane, sg1 = c1 * 64 + lane;     // 16B segment idx 0..511
    const int r0 = sg0 >> 2, r1 = sg1 >> 2;                   // tile row 0..127
    const int csg0 = (sg0 & 3) ^ ((r0 >> 1) & 3);             // global segment (de-swizzled)
    const int csg1 = (sg1 & 3) ^ ((r1 >> 1) & 3);
    const bf16* gA0 = A  + (size_t)(bm + r0) * DM + csg0 * 8;
    const bf16* gA1 = A  + (size_t)(bm + r1) * DM + csg1 * 8;
    const bf16* gB0 = Wt + (size_t)(bn + r0) * DM + csg0 * 8;
    const bf16* gB1 = Wt + (size_t)(bn + r1) * DM + csg1 * 8;

#define STG(buf, tt) do { \
    GLL16(gA0 + (size_t)(tt) * 32, &AsF[buf][c0 * 512]); \
    GLL16(gA1 + (size_t)(tt) * 32, &AsF[buf][c1 * 512]); \
    GLL16(gB0 + (size_t)(tt) * 32, &BsF[buf][c0 * 512]); \
    GLL16(gB1 + (size_t)(tt) * 32, &BsF[buf][c1 * 512]); \
} while (0)

    // prologue: tiles 0,1 in flight immediately
    STG(0, 0);
    STG(1, 1);

    // fragment read offsets (loop-invariant; swizzled)
    int offA[4], offB[4];
#pragma unroll
    for (int mt = 0; mt < 4; mt++) {
        const int r = wm + mt * 16 + l16;
        offA[mt] = r * 32 + ((quad ^ ((r >> 1) & 3)) << 3);
    }
#pragma unroll
    for (int nt = 0; nt < 4; nt++) {
        const int r = wn + nt * 16 + l16;
        offB[nt] = r * 32 + ((quad ^ ((r >> 1) & 3)) << 3);
    }

    f32x4 zero = {0.f, 0.f, 0.f, 0.f};
    f32x4 acc[4][4];
#pragma unroll
    for (int mt = 0; mt < 4; mt++)
#pragma unroll
        for (int nt = 0; nt < 4; nt++) acc[mt][nt] = zero;

    DRAIN(4);      // tile 0 landed (tile 1 still in flight)
    BARRIER();

#pragma unroll
    for (int tk = 0; tk < 32; tk++) {
        const int cur = tk % 3;
        if (tk < 31) {
            const int nb = (tk + 2) % 3;
            const int ts = (tk + 2 > 31) ? 31 : (tk + 2);   // clamp: restage L2-hot tile 31
            STG(nb, ts);
        }
        const bf16* ab = &AsF[cur][0];
        const bf16* bb = &BsF[cur][0];
        bf16x8 af[4], bfr[4];
#pragma unroll
        for (int mt = 0; mt < 4; mt++) af[mt]  = *(const bf16x8*)(ab + offA[mt]);
#pragma unroll
        for (int nt = 0; nt < 4; nt++) bfr[nt] = *(const bf16x8*)(bb + offB[nt]);
#pragma unroll
        for (int mt = 0; mt < 4; mt++)
#pragma unroll
            for (int nt = 0; nt < 4; nt++)
                acc[mt][nt] = MFMA16(af[mt], bfr[nt], acc[mt][nt]);
        if (tk < 31) {
            DRAIN(4);      // stage(tk+1) landed; stage(tk+2) stays in flight
            BARRIER();
        }
    }
#undef STG

    float bv[4], invf[4];
#pragma unroll
    for (int nt = 0; nt < 4; nt++) {
        const int col = bn + wn + nt * 16 + l16;
        bv[nt] = bias[col];
        if (MODE == 0) {
            // rope inv_freq for pair index i = (col%64)/2 : 10000^(-i/32)
            const int i = (col & 63) >> 1;
            invf[nt] = __builtin_exp2f(-0.41524101186092029f * (float)i);
        }
    }
    const int odd = l16 & 1;

    if (MODE == 0 && z == 2) {
        // V: store transposed to vt [B,H,D,S]; 4 consecutive s per lane -> bf16x4
#pragma unroll
        for (int mt = 0; mt < 4; mt++) {
            const int row0 = bm + wm + mt * 16 + quad * 4;
            const int b = row0 >> 11, s0 = row0 & (SEQ - 1);
#pragma unroll
            for (int nt = 0; nt < 4; nt++) {
                const int col = bn + wn + nt * 16 + l16;
                const int h = col >> 6, dd = col & 63;
                bf16x4 o;
#pragma unroll
                for (int rg = 0; rg < 4; rg++) o[rg] = (bf16)(acc[mt][nt][rg] + bv[nt]);
                *(bf16x4*)(vt + ((size_t)((b * NH + h) * HD + dd)) * SEQ + s0) = o;
            }
        }
        return;
    }

#pragma unroll
    for (int mt = 0; mt < 4; mt++) {
#pragma unroll
        for (int nt = 0; nt < 4; nt++) {
            const int col = bn + wn + nt * 16 + l16;
#pragma unroll
            for (int rg = 0; rg < 4; rg++) {
                const int row = bm + wm + mt * 16 + quad * 4 + rg;
                float val = acc[mt][nt][rg] + bv[nt];
                if (MODE == 0) {
                    const int b = row >> 11, s = row & (SEQ - 1);
                    const int h = col >> 6, dd = col & 63;
                    // fused RoPE on q,k (q also pre-scaled by 1/8); partner elem
                    // (col^1) lives in lane l16^1, same regs -> shfl_xor(1)
                    const float partner = __shfl_xor(val, 1);
                    float sn, cs;
                    __sincosf((float)s * invf[nt], &sn, &cs);
                    val = odd ? (val * cs + partner * sn)
                              : (val * cs - partner * sn);
                    if (z == 0) val *= 0.125f;
                    ((bf16*)out)[(size_t)z * TEN +
                                 (((size_t)(b * NH + h)) * SEQ + s) * HD + dd] = (bf16)val;
                } else {
                    ((float*)out)[(size_t)row * DM + col] = val;
                }
            }
        }
    }
}

// ---------------------------------------------------------------- flash attention (causal)
// grid: (bh=64, 16). qb = 15 - blockIdx.y (heavy-first). One 128-row q-block per block.
// __launch_bounds__(256,2): (256,4) made the allocator target 64 VGPRs -> spilled
// accumulators to scratch. Wave w owns rows w*32..w*32+31 (2 m-tiles). K/V in
// 3-deep rotating XOR-swizzled LDS buffers (depth-2 prefetch, DRAIN(4) counted,
// one barrier per kv-tile — same pipeline as k_gemm; removes the per-tile
// vmcnt(0) full-latency stall). P in wave-private swizzled LDS (no barrier).
// Softmax: fixed offset -10 in acc init; row-sum deferred to epilogue.
// Wave-level skip of fully-masked corner (drain/barrier stay wave-uniform).
__global__ __launch_bounds__(256, 2) void k_attn(const bf16* __restrict__ q,
                                                 const bf16* __restrict__ k,
                                                 const bf16* __restrict__ vt,
                                                 bf16* __restrict__ y) {
    __shared__ __align__(1024) bf16 KsF[3][4096];      // 3 x 8 KB [kv][d] swizzled
    __shared__ __align__(1024) bf16 VsF[3][4096];      // 3 x 8 KB [d][kv] swizzled
    __shared__ __align__(1024) bf16 PsF[4 * 32 * 64];  // 16 KB per-wave P scratch, swizzled
    const int t = threadIdx.x;
    const int w = t >> 6, lane = t & 63, quad = lane >> 4, l16 = lane & 15;
    const int bh = blockIdx.x;                // bh fastest => y-blocks of one bh share an XCD
    const int qb = 15 - (int)blockIdx.y;      // heavy blocks dispatch first
    const int b = bh >> 4, h = bh & 15;

    // staging lane mapping: chunk = 8 rows x 64 elems (1 KB); lane -> (row, stored seg)
    const int srow = lane >> 3;                       // row within chunk
    const int gseg = (lane & 7) ^ srow;               // global seg fetched (de-swizzle)
    const int c0 = w, c1 = w + 4;                     // this wave's chunks

    const bf16* kbase = k  + (size_t)bh * SEQ * HD;
    const bf16* vbase = vt + (size_t)bh * HD * SEQ;
    const float NEG_INF = -__builtin_inff();

    // per-kv-tile source offsets (tile-invariant part)
    const int koff0 = (c0 * 8 + srow) * HD + gseg * 8;
    const int koff1 = (c1 * 8 + srow) * HD + gseg * 8;
    const int voff0 = (c0 * 8 + srow) * SEQ + gseg * 8;
    const int voff1 = (c1 * 8 + srow) * SEQ + gseg * 8;

#define STGKV(buf, tt) do { \
    GLL16(kbase + (size_t)(tt) * 64 * HD + koff0, &KsF[buf][c0 * 512]); \
    GLL16(kbase + (size_t)(tt) * 64 * HD + koff1, &KsF[buf][c1 * 512]); \
    GLL16(vbase + (size_t)(tt) * 64 + voff0, &VsF[buf][c0 * 512]); \
    GLL16(vbase + (size_t)(tt) * 64 + voff1, &VsF[buf][c1 * 512]); \
} while (0)

    // Q fragments: 2 m-tiles, A-layout (global loads issued before staging DMAs)
    bf16x8 qf[2][2];
#pragma unroll
    for (int mt = 0; mt < 2; mt++) {
        const bf16* qrow = q + ((size_t)bh * SEQ + qb * 128 + w * 32 + mt * 16 + l16) * HD;
        qf[mt][0] = *(const bf16x8*)(qrow + quad * 8);
        qf[mt][1] = *(const bf16x8*)(qrow + 32 + quad * 8);
    }

    const int ktmax = 2 * qb + 1;
    STGKV(0, 0);
    STGKV(1, 1);

    // fragment read offsets within a K/V buffer (kt-invariant, swizzled):
    // row*64 + ((seg ^ (row&7))<<3); identical for K and V
    int off_kv[4][2];
#pragma unroll
    for (int nt = 0; nt < 4; nt++) {
        const int r = nt * 16 + l16;
#pragma unroll
        for (int hh = 0; hh < 2; hh++) {
            const int sg = hh * 4 + quad;
            off_kv[nt][hh] = r * 64 + ((sg ^ (r & 7)) << 3);
        }
    }
    const bf16 *pf_p[2][2];
#pragma unroll
    for (int mt = 0; mt < 2; mt++) {
        const int r = mt * 16 + l16;
#pragma unroll
        for (int hh = 0; hh < 2; hh++) {
            const int sg = hh * 4 + quad;
            pf_p[mt][hh] = PsF + w * 2048 + r * 64 + ((sg ^ (r & 7)) << 3);
        }
    }

    f32x4 zero = {0.f, 0.f, 0.f, 0.f};
    f32x4 minus10 = {-10.f, -10.f, -10.f, -10.f};
    f32x4 acc_o[2][4];
    float l_acc[2][4];
#pragma unroll
    for (int mt = 0; mt < 2; mt++)
#pragma unroll
        for (int nt = 0; nt < 4; nt++) acc_o[mt][nt] = zero;
#pragma unroll
    for (int mt = 0; mt < 2; mt++)
#pragma unroll
        for (int rg = 0; rg < 4; rg++) l_acc[mt][rg] = 0.f;

    DRAIN(4);      // tile 0 landed (tile 1 in flight; q-frag loads forced earlier by MFMA use)
    BARRIER();

    int cur = 0, nb = 2;
    for (int kt = 0; kt <= ktmax; kt++) {
        if (kt < ktmax) {
            const int ts = (kt + 2 > ktmax) ? ktmax : (kt + 2);  // clamp: restage hot tile
            STGKV(nb, ts);
        }
        const bf16* kb_ = &KsF[0][0] + cur * 4096;
        const bf16* vb_ = &VsF[0][0] + cur * 4096;

        const int d = qb * 128 + w * 32 - kt * 64;   // wave-row offset vs kv base
        if (d > -32) {                      // else fully masked: skip (wave-uniform)
            // ---- S = Q K^T - 10
            f32x4 accs[2][4];
#pragma unroll
            for (int nt = 0; nt < 4; nt++) {
                const bf16x8 kf0 = *(const bf16x8*)(kb_ + off_kv[nt][0]);
                const bf16x8 kf1 = *(const bf16x8*)(kb_ + off_kv[nt][1]);
#pragma unroll
                for (int mt = 0; mt < 2; mt++) {
                    f32x4 a = minus10;
                    a = MFMA16(qf[mt][0], kf0, a);
                    a = MFMA16(qf[mt][1], kf1, a);
                    accs[mt][nt] = a;
                }
            }
            // ---- causal mask (only when the 64-kv tile straddles this wave's rows)
            if (d < 64) {
#pragma unroll
                for (int mt = 0; mt < 2; mt++) {
                    const int qr = d + mt * 16 + quad * 4;
#pragma unroll
                    for (int nt = 0; nt < 4; nt++) {
                        const int kv = nt * 16 + l16;
#pragma unroll
                        for (int rg = 0; rg < 4; rg++)
                            if (kv > qr + rg) accs[mt][nt][rg] = NEG_INF;
                    }
                }
            }
            // ---- p = exp(S-10); per-lane row-sum; P -> swizzled wave-private LDS
#pragma unroll
            for (int mt = 0; mt < 2; mt++) {
#pragma unroll
                for (int nt = 0; nt < 4; nt++) {
#pragma unroll
                    for (int rg = 0; rg < 4; rg++) {
                        const float p = __expf(accs[mt][nt][rg]);
                        l_acc[mt][rg] += p;
                        const int prow = mt * 16 + quad * 4 + rg;
                        const int psg  = (nt * 2 + (l16 >> 3)) ^ (prow & 7);
                        PsF[w * 2048 + prow * 64 + psg * 8 + (l16 & 7)] = (bf16)p;
                    }
                }
            }
            // ---- O += P V (in-order DS pipe: no barrier for wave-private P)
            bf16x8 pf[2][2];
#pragma unroll
            for (int mt = 0; mt < 2; mt++) {
                pf[mt][0] = *(const bf16x8*)pf_p[mt][0];
                pf[mt][1] = *(const bf16x8*)pf_p[mt][1];
            }
#pragma unroll
            for (int nt = 0; nt < 4; nt++) {
                const bf16x8 vf0 = *(const bf16x8*)(vb_ + off_kv[nt][0]);
                const bf16x8 vf1 = *(const bf16x8*)(vb_ + off_kv[nt][1]);
#pragma unroll
                for (int mt = 0; mt < 2; mt++) {
                    acc_o[mt][nt] = MFMA16(pf[mt][0], vf0, acc_o[mt][nt]);
                    acc_o[mt][nt] = MFMA16(pf[mt][1], vf1, acc_o[mt][nt]);
                }
            }
        }
        if (kt < ktmax) {
            DRAIN(4);      // stage(kt+1) landed; stage(kt+2) in flight
            BARRIER();
        }
        cur = (cur == 2) ? 0 : cur + 1;
        nb  = (nb  == 2) ? 0 : nb  + 1;
    }
#undef STGKV

    // ---- epilogue: reduce l over the 16 lanes holding each row, normalize, store
#pragma unroll
    for (int mt = 0; mt < 2; mt++) {
#pragma unroll
        for (int rg = 0; rg < 4; rg++) {
            float rs = l_acc[mt][rg];
            rs += __shfl_xor(rs, 1);
            rs += __shfl_xor(rs, 2);
            rs += __shfl_xor(rs, 4);
            rs += __shfl_xor(rs, 8);
            const float inv = 1.0f / rs;
            const int s = qb * 128 + w * 32 + mt * 16 + quad * 4 + rg;
#pragma unroll
            for (int nt = 0; nt < 4; nt++) {
                const float val = acc_o[mt][nt][rg] * inv;
                y[((size_t)(b * SEQ + s)) * DM + h * HD + nt * 16 + l16] = (bf16)val;
            }
        }
    }
}

// ---------------------------------------------------------------- launch
extern "C" void kernel_launch(void* const* d_in, const int* in_sizes, int n_in,
                              void* d_out, int out_size, void* d_ws, size_t ws_size,
                              hipStream_t stream) {
    const float* x  = (const float*)d_in[0];
    const float* Wq = (const float*)d_in[1];
    const float* bq = (const float*)d_in[2];
    const float* Wk = (const float*)d_in[3];
    const float* bk = (const float*)d_in[4];
    const float* Wv = (const float*)d_in[5];
    const float* bv = (const float*)d_in[6];
    const float* Wo = (const float*)d_in[7];
    const float* bo = (const float*)d_in[8];

    // Workspace layout (88 MB total).
    char* ws = (char*)d_ws;
    bf16* xb   = (bf16*)(ws);                       // 16 MB: x bf16; reused as attn out y
    bf16* wall = (bf16*)(ws + (16ull << 20));       //  8 MB: Wq^T,Wk^T,Wv^T,Wo^T bf16
    bf16* qb   = (bf16*)(ws + (24ull << 20));       // 16 MB (q at +0, k at +TEN)
    bf16* kb   = (bf16*)(ws + (40ull << 20));       // 16 MB
    bf16* vtb  = (bf16*)(ws + (72ull << 20));       // 16 MB: V^T [B,H,D,S] (written by k_gemm<0> z=2)
    bf16* wot  = wall + 3ull * DM * DM;

    k_prep<<<dim3(16, 16, 5), 256, 0, stream>>>(x, Wq, Wk, Wv, Wo, wall, xb);
    k_gemm<0><<<dim3(64, 8, 3), 256, 0, stream>>>(xb, wall, bq, bk, bv, vtb, qb);
    k_attn<<<dim3(64, 16), 256, 0, stream>>>(qb, kb, vtb, xb);
    k_gemm<1><<<dim3(64, 8, 1), 256, 0, stream>>>(xb, wot, bo, bo, bo, vtb, d_out);
}

// Round 3
// 250.749 us; speedup vs baseline: 1.0254x; 1.0119x over previous
//
#include <hip/hip_runtime.h>

typedef __bf16 bf16;
typedef __bf16 bf16x2 __attribute__((ext_vector_type(2)));
typedef __bf16 bf16x4 __attribute__((ext_vector_type(4)));
typedef __bf16 bf16x8 __attribute__((ext_vector_type(8)));
typedef float  f32x4  __attribute__((ext_vector_type(4)));

#define MFMA16(a,b,c) __builtin_amdgcn_mfma_f32_16x16x32_bf16(a,b,c,0,0,0)
// async global->LDS DMA, 16B per lane; LDS dest is wave-uniform base + lane*16
#define GLL16(g, l) __builtin_amdgcn_global_load_lds( \
    (const __attribute__((address_space(1))) unsigned char*)(g), \
    (__attribute__((address_space(3))) unsigned char*)(l), 16, 0, 0)
#define BARRIER() asm volatile("s_barrier" ::: "memory")
#define DRAIN(n)  asm volatile("s_waitcnt vmcnt(" #n ")" ::: "memory")

constexpr int SEQ   = 2048;
constexpr int NH    = 16;
constexpr int HD    = 64;
constexpr int BATCH = 4;
constexpr int DM    = 1024;          // model dim
constexpr size_t TEN = (size_t)BATCH * NH * SEQ * HD;   // 8,388,608 elems per tensor

// ---------------------------------------------------------------- prep: weight transpose (z=0..3) + x convert (z=4)
__global__ __launch_bounds__(256) void k_prep(const float* __restrict__ x,
                                              const float* __restrict__ W0,
                                              const float* __restrict__ W1,
                                              const float* __restrict__ W2,
                                              const float* __restrict__ W3,
                                              bf16* __restrict__ Wt_all,
                                              bf16* __restrict__ xb) {
    __shared__ float T[64][65];
    const int z = blockIdx.z;
    const int t = threadIdx.x;
    if (z == 4) {
        // convert x (fp32 -> bf16): 256 blocks x 256 threads x 128 elems
        const int bi = blockIdx.y * 16 + blockIdx.x;
#pragma unroll
        for (int c = 0; c < 16; c++) {
            const size_t idx = (size_t)c * 524288 + ((size_t)bi * 256 + t) * 8;
            float4 f0 = *(const float4*)(x + idx);
            float4 f1 = *(const float4*)(x + idx + 4);
            bf16x8 o;
            o[0] = (bf16)f0.x; o[1] = (bf16)f0.y; o[2] = (bf16)f0.z; o[3] = (bf16)f0.w;
            o[4] = (bf16)f1.x; o[5] = (bf16)f1.y; o[6] = (bf16)f1.z; o[7] = (bf16)f1.w;
            *(bf16x8*)(xb + idx) = o;
        }
        return;
    }
    const float* W = (z == 0) ? W0 : (z == 1) ? W1 : (z == 2) ? W2 : W3;
    bf16* Wt = Wt_all + (size_t)z * DM * DM;
    const int kb = blockIdx.x, nb = blockIdx.y;
    const int rl = t >> 2, seg = t & 3;
    const float* src = W + (size_t)(kb * 64 + rl) * DM + nb * 64 + seg * 16;
#pragma unroll
    for (int j4 = 0; j4 < 4; j4++) {
        float4 f = *(const float4*)(src + j4 * 4);
        T[rl][seg * 16 + j4 * 4 + 0] = f.x;
        T[rl][seg * 16 + j4 * 4 + 1] = f.y;
        T[rl][seg * 16 + j4 * 4 + 2] = f.z;
        T[rl][seg * 16 + j4 * 4 + 3] = f.w;
    }
    __syncthreads();
    bf16* dst = Wt + (size_t)(nb * 64 + rl) * DM + kb * 64 + seg * 16;
    bf16x8 o0, o1;
#pragma unroll
    for (int j = 0; j < 8; j++) {
        o0[j] = (bf16)T[seg * 16 + j][rl];
        o1[j] = (bf16)T[seg * 16 + 8 + j][rl];
    }
    *(bf16x8*)dst = o0;
    *(bf16x8*)(dst + 8) = o1;
}

// ---------------------------------------------------------------- GEMM: 256x128 tile, BK=64, 4-phase/iter 8-phase-style pipeline
// Geometry chosen for ZERO grid tail: MODE0 grid 32x24 = 768 blocks = exactly
// 3 rounds at 1 block/CU; MODE1 grid 32x8 = 256 = exactly 1 round.
// 512 threads = 8 waves, 2M x 4N; per-wave C = 128x32 = acc[8][2].
// LDS 128 KB: A triple-buffered (3 x 32 KB, K-tile 256x64) + B double-buffered
// (2 x 16 KB, 128x64). XOR swizzle seg' = seg ^ (row&7) (bank-conflict-0,
// verified by counters in prior rounds); staging pre-inverse-swizzles the
// global source, reads apply the same involution.
// Iteration i computes K-tiles Te=2i (A in LA[ae], B in LB[0]) and To=2i+1
// (LA[ao], LB[1]) in 4 phases of 16 MFMA each:
//   P1: read B(Te) frags (held 2 phases) + A(Te) rows 0..63; stage A(Te+2)->LA[an]
//   P2: read A(Te) rows 64..127;  stage B(Te+2)->LB[0]; DRAIN(6)
//   P3: read B(To) + A(To) 0..63; stage A(To+2)->LA[ae]
//   P4: read A(To) 64..127;       stage B(To+2)->LB[1]; DRAIN(6)
// Steady-state queue (GLLs/wave): enter P1 with 6 in flight {A(To)4,B(To)2};
// P1 +4, P2 +2 -> 12; DRAIN(6) completes exactly {A(To),B(To)} needed at P3;
// P3 +4, P4 +2 -> 12; DRAIN(6) completes {A(Te+2),B(Te+2)} needed at next P1.
// Buffer-write safety: every staged buffer's last reader finished >=1 barrier
// before the GLL issues (A mod-3 rotation / B alternation guarantee it).
// Never vmcnt(0) in the loop (T4); setprio around MFMA (T5). K order ascending
// 32-chunks -> bit-identical accumulation vs previous rounds.
// MODE 0: z=by>>3 (q/k/v); q,k: fused RoPE scatter to [B,H,S,D]; v: transposed
//         scatter to vt [B,H,D,S]. MODE 1: out fp32 [row][col].
template <int MODE>
__global__ __launch_bounds__(512, 1) void k_gemm(const bf16* __restrict__ A,
                                                 const bf16* __restrict__ Wt0,
                                                 const float* __restrict__ b0,
                                                 const float* __restrict__ b1,
                                                 const float* __restrict__ b2,
                                                 bf16* __restrict__ vt,
                                                 void* __restrict__ out) {
    __shared__ __align__(1024) bf16 LA[3][16384];   // 96 KB
    __shared__ __align__(1024) bf16 LB[2][8192];    // 32 KB
    const int t = threadIdx.x;
    const int w = t >> 6, lane = t & 63, quad = lane >> 4, l16 = lane & 15;
    const int bm = blockIdx.x * 256;
    const int by = blockIdx.y;
    const int z  = (MODE == 0) ? (by >> 3) : 0;
    const int bn = (MODE == 0) ? ((by & 7) * 128) : (by * 128);
    const bf16* Wt = Wt0 + (size_t)z * DM * DM;
    const float* bias = (z == 0) ? b0 : (z == 1) ? b1 : b2;
    const int wm = (w >> 2) * 128, wn = (w & 3) * 32;

    // staging lane mapping: chunk = 8 rows x 64 cols (1 KB); lane -> (row, seg)
    const int srow = lane >> 3;
    const int sseg = (lane & 7) ^ srow;               // global seg (de-swizzled)
    const bf16* gA = A  + (size_t)(bm + w * 8 + srow) * DM + sseg * 8;
    const bf16* gB = Wt + (size_t)(bn + w * 8 + srow) * DM + sseg * 8;

// A-tile = 32 chunks; call c stages chunks c*16+w, c*16+w+8 (rows c*128+w*8 +{0,64})
#define STGA_P(lp, tt, c) do { \
    const bf16* _g = gA + (size_t)(c) * 128 * DM + (size_t)(tt) * 64; \
    bf16* _l = (lp) + ((c) * 16 + w) * 512; \
    GLL16(_g, _l); GLL16(_g + 64 * DM, _l + 4096); \
} while (0)
// B-tile = 16 chunks; wave stages chunks w, w+8
#define STGB_P(lp, tt) do { \
    const bf16* _g = gB + (size_t)(tt) * 64; \
    bf16* _l = (lp) + w * 512; \
    GLL16(_g, _l); GLL16(_g + 64 * DM, _l + 4096); \
} while (0)

    // fragment read swizzled seg offsets (elements): seg k-slice 0 / 1
    const int sA0 = (quad ^ (l16 & 7)) << 3;
    const int sA1 = ((4 + quad) ^ (l16 & 7)) << 3;

    f32x4 zero = {0.f, 0.f, 0.f, 0.f};
    f32x4 acc[8][2];
#pragma unroll
    for (int mt = 0; mt < 8; mt++)
#pragma unroll
        for (int nt = 0; nt < 2; nt++) acc[mt][nt] = zero;
    bf16x8 bfr[2][2];

#define PH(la_, lb_, mb, READB, STAGE_STMT, DRAIN_STMT) do { \
    const bf16* _la = (la_); \
    if (READB) { \
        const bf16* _lb = (lb_); \
        _Pragma("unroll") \
        for (int nt = 0; nt < 2; nt++) { \
            const int r = (wn + nt * 16 + l16) * 64; \
            bfr[nt][0] = *(const bf16x8*)(_lb + r + sA0); \
            bfr[nt][1] = *(const bf16x8*)(_lb + r + sA1); \
        } \
    } \
    bf16x8 af[4][2]; \
    _Pragma("unroll") \
    for (int mi = 0; mi < 4; mi++) { \
        const int r = (wm + ((mb) + mi) * 16 + l16) * 64; \
        af[mi][0] = *(const bf16x8*)(_la + r + sA0); \
        af[mi][1] = *(const bf16x8*)(_la + r + sA1); \
    } \
    STAGE_STMT; \
    DRAIN_STMT; \
    BARRIER(); \
    __builtin_amdgcn_s_setprio(1); \
    _Pragma("unroll") \
    for (int mi = 0; mi < 4; mi++) \
        _Pragma("unroll") \
        for (int nt = 0; nt < 2; nt++) { \
            f32x4 a = acc[(mb) + mi][nt]; \
            a = MFMA16(af[mi][0], bfr[nt][0], a); \
            a = MFMA16(af[mi][1], bfr[nt][1], a); \
            acc[(mb) + mi][nt] = a; \
        } \
    __builtin_amdgcn_s_setprio(0); \
    BARRIER(); \
} while (0)

    // prologue: A(T0),B(T0),A(T1),B(T1) in flight; complete first 6 (=T0)
    STGA_P(&LA[0][0], 0, 0); STGA_P(&LA[0][0], 0, 1); STGB_P(&LB[0][0], 0);
    STGA_P(&LA[1][0], 1, 0); STGA_P(&LA[1][0], 1, 1); STGB_P(&LB[1][0], 1);
    DRAIN(6);
    BARRIER();

    int ae = 0, ao = 1, an = 2;
    for (int i = 0; i < 8; i++) {
        const int tE = (i < 7) ? 2 * i + 2 : 15;   // clamp: restage L2-hot T15
        const int tO = (i < 7) ? 2 * i + 3 : 15;
        bf16* lae = &LA[0][0] + ae * 16384;
        bf16* lao = &LA[0][0] + ao * 16384;
        bf16* lan = &LA[0][0] + an * 16384;
        PH(lae, &LB[0][0], 0, 1, { STGA_P(lan, tE, 0); STGA_P(lan, tE, 1); }, );
        PH(lae, (const bf16*)0, 4, 0, STGB_P(&LB[0][0], tE), DRAIN(6));
        PH(lao, &LB[1][0], 0, 1, { STGA_P(lae, tO, 0); STGA_P(lae, tO, 1); }, );
        PH(lao, (const bf16*)0, 4, 0, STGB_P(&LB[1][0], tO), DRAIN(6));
        const int tmp = ae; ae = an; an = ao; ao = tmp;
    }
#undef PH
#undef STGA_P
#undef STGB_P

    // ---------------- epilogue
    float bv[2], invf[2];
#pragma unroll
    for (int nt = 0; nt < 2; nt++) {
        const int col = bn + wn + nt * 16 + l16;
        bv[nt] = bias[col];
        if (MODE == 0) {
            const int ip = (col & 63) >> 1;   // rope pair index: 10000^(-ip/32)
            invf[nt] = __builtin_exp2f(-0.41524101186092029f * (float)ip);
        }
    }
    const int odd = l16 & 1;

    if (MODE == 0 && z == 2) {
        // V: store transposed to vt [B,H,D,S]; 4 consecutive s per lane -> bf16x4
#pragma unroll
        for (int mt = 0; mt < 8; mt++) {
            const int row0 = bm + wm + mt * 16 + quad * 4;
            const int b = row0 >> 11, s0 = row0 & (SEQ - 1);
#pragma unroll
            for (int nt = 0; nt < 2; nt++) {
                const int col = bn + wn + nt * 16 + l16;
                const int h = col >> 6, dd = col & 63;
                bf16x4 o;
#pragma unroll
                for (int rg = 0; rg < 4; rg++) o[rg] = (bf16)(acc[mt][nt][rg] + bv[nt]);
                *(bf16x4*)(vt + ((size_t)((b * NH + h) * HD + dd)) * SEQ + s0) = o;
            }
        }
        return;
    }

#pragma unroll
    for (int mt = 0; mt < 8; mt++) {
#pragma unroll
        for (int nt = 0; nt < 2; nt++) {
            const int col = bn + wn + nt * 16 + l16;
#pragma unroll
            for (int rg = 0; rg < 4; rg++) {
                const int row = bm + wm + mt * 16 + quad * 4 + rg;
                float val = acc[mt][nt][rg] + bv[nt];
                if (MODE == 0) {
                    const int b = row >> 11, s = row & (SEQ - 1);
                    const int h = col >> 6, dd = col & 63;
                    // fused RoPE on q,k (q pre-scaled 1/8); partner (col^1) is in
                    // lane l16^1, same regs -> shfl_xor(1)
                    const float partner = __shfl_xor(val, 1);
                    float sn, cs;
                    __sincosf((float)s * invf[nt], &sn, &cs);
                    val = odd ? (val * cs + partner * sn)
                              : (val * cs - partner * sn);
                    if (z == 0) val *= 0.125f;
                    ((bf16*)out)[(size_t)z * TEN +
                                 (((size_t)(b * NH + h)) * SEQ + s) * HD + dd] = (bf16)val;
                } else {
                    ((float*)out)[(size_t)row * DM + col] = val;
                }
            }
        }
    }
}

// ---------------------------------------------------------------- flash attention (causal)
// grid: (bh=64, 16). qb = 15 - blockIdx.y (heavy-first). One 128-row q-block per block.
// Wave w owns rows w*32..w*32+31 (2 m-tiles). K/V in 3-deep rotating XOR-swizzled
// LDS buffers (depth-2 prefetch, counted DRAIN(4), one barrier per kv-tile).
// P in wave-private swizzled LDS (no barrier). Softmax: fixed offset -10 in acc
// init; row-sum deferred to epilogue. Wave-level skip of fully-masked corner.
__global__ __launch_bounds__(256, 2) void k_attn(const bf16* __restrict__ q,
                                                 const bf16* __restrict__ k,
                                                 const bf16* __restrict__ vt,
                                                 bf16* __restrict__ y) {
    __shared__ __align__(1024) bf16 KsF[3][4096];      // 3 x 8 KB [kv][d] swizzled
    __shared__ __align__(1024) bf16 VsF[3][4096];      // 3 x 8 KB [d][kv] swizzled
    __shared__ __align__(1024) bf16 PsF[4 * 32 * 64];  // 16 KB per-wave P scratch, swizzled
    const int t = threadIdx.x;
    const int w = t >> 6, lane = t & 63, quad = lane >> 4, l16 = lane & 15;
    const int bh = blockIdx.x;                // bh fastest => qb-blocks of one bh share an XCD
    const int qb = 15 - (int)blockIdx.y;      // heavy blocks dispatch first
    const int b = bh >> 4, h = bh & 15;

    const int srow = lane >> 3;                       // row within chunk
    const int gseg = (lane & 7) ^ srow;               // global seg fetched (de-swizzle)
    const int c0 = w, c1 = w + 4;                     // this wave's chunks

    const bf16* kbase = k  + (size_t)bh * SEQ * HD;
    const bf16* vbase = vt + (size_t)bh * HD * SEQ;
    const float NEG_INF = -__builtin_inff();

    const int koff0 = (c0 * 8 + srow) * HD + gseg * 8;
    const int koff1 = (c1 * 8 + srow) * HD + gseg * 8;
    const int voff0 = (c0 * 8 + srow) * SEQ + gseg * 8;
    const int voff1 = (c1 * 8 + srow) * SEQ + gseg * 8;

#define STGKV(buf, tt) do { \
    GLL16(kbase + (size_t)(tt) * 64 * HD + koff0, &KsF[buf][c0 * 512]); \
    GLL16(kbase + (size_t)(tt) * 64 * HD + koff1, &KsF[buf][c1 * 512]); \
    GLL16(vbase + (size_t)(tt) * 64 + voff0, &VsF[buf][c0 * 512]); \
    GLL16(vbase + (size_t)(tt) * 64 + voff1, &VsF[buf][c1 * 512]); \
} while (0)

    // Q fragments: 2 m-tiles, A-layout
    bf16x8 qf[2][2];
#pragma unroll
    for (int mt = 0; mt < 2; mt++) {
        const bf16* qrow = q + ((size_t)bh * SEQ + qb * 128 + w * 32 + mt * 16 + l16) * HD;
        qf[mt][0] = *(const bf16x8*)(qrow + quad * 8);
        qf[mt][1] = *(const bf16x8*)(qrow + 32 + quad * 8);
    }

    const int ktmax = 2 * qb + 1;
    STGKV(0, 0);
    STGKV(1, 1);

    int off_kv[4][2];
#pragma unroll
    for (int nt = 0; nt < 4; nt++) {
        const int r = nt * 16 + l16;
#pragma unroll
        for (int hh = 0; hh < 2; hh++) {
            const int sg = hh * 4 + quad;
            off_kv[nt][hh] = r * 64 + ((sg ^ (r & 7)) << 3);
        }
    }
    const bf16 *pf_p[2][2];
#pragma unroll
    for (int mt = 0; mt < 2; mt++) {
        const int r = mt * 16 + l16;
#pragma unroll
        for (int hh = 0; hh < 2; hh++) {
            const int sg = hh * 4 + quad;
            pf_p[mt][hh] = PsF + w * 2048 + r * 64 + ((sg ^ (r & 7)) << 3);
        }
    }

    f32x4 zero = {0.f, 0.f, 0.f, 0.f};
    f32x4 minus10 = {-10.f, -10.f, -10.f, -10.f};
    f32x4 acc_o[2][4];
    float l_acc[2][4];
#pragma unroll
    for (int mt = 0; mt < 2; mt++)
#pragma unroll
        for (int nt = 0; nt < 4; nt++) acc_o[mt][nt] = zero;
#pragma unroll
    for (int mt = 0; mt < 2; mt++)
#pragma unroll
        for (int rg = 0; rg < 4; rg++) l_acc[mt][rg] = 0.f;

    DRAIN(4);      // tile 0 landed (tile 1 in flight)
    BARRIER();

    int cur = 0, nb = 2;
    for (int kt = 0; kt <= ktmax; kt++) {
        if (kt < ktmax) {
            const int ts = (kt + 2 > ktmax) ? ktmax : (kt + 2);  // clamp: restage hot tile
            STGKV(nb, ts);
        }
        const bf16* kb_ = &KsF[0][0] + cur * 4096;
        const bf16* vb_ = &VsF[0][0] + cur * 4096;

        const int d = qb * 128 + w * 32 - kt * 64;   // wave-row offset vs kv base
        if (d > -32) {                      // else fully masked: skip (wave-uniform)
            // ---- S = Q K^T - 10
            f32x4 accs[2][4];
#pragma unroll
            for (int nt = 0; nt < 4; nt++) {
                const bf16x8 kf0 = *(const bf16x8*)(kb_ + off_kv[nt][0]);
                const bf16x8 kf1 = *(const bf16x8*)(kb_ + off_kv[nt][1]);
#pragma unroll
                for (int mt = 0; mt < 2; mt++) {
                    f32x4 a = minus10;
                    a = MFMA16(qf[mt][0], kf0, a);
                    a = MFMA16(qf[mt][1], kf1, a);
                    accs[mt][nt] = a;
                }
            }
            // ---- causal mask
            if (d < 64) {
#pragma unroll
                for (int mt = 0; mt < 2; mt++) {
                    const int qr = d + mt * 16 + quad * 4;
#pragma unroll
                    for (int nt = 0; nt < 4; nt++) {
                        const int kv = nt * 16 + l16;
#pragma unroll
                        for (int rg = 0; rg < 4; rg++)
                            if (kv > qr + rg) accs[mt][nt][rg] = NEG_INF;
                    }
                }
            }
            // ---- p = exp(S-10); per-lane row-sum; P -> swizzled wave-private LDS
#pragma unroll
            for (int mt = 0; mt < 2; mt++) {
#pragma unroll
                for (int nt = 0; nt < 4; nt++) {
#pragma unroll
                    for (int rg = 0; rg < 4; rg++) {
                        const float p = __expf(accs[mt][nt][rg]);
                        l_acc[mt][rg] += p;
                        const int prow = mt * 16 + quad * 4 + rg;
                        const int psg  = (nt * 2 + (l16 >> 3)) ^ (prow & 7);
                        PsF[w * 2048 + prow * 64 + psg * 8 + (l16 & 7)] = (bf16)p;
                    }
                }
            }
            // ---- O += P V (in-order DS pipe: no barrier for wave-private P)
            bf16x8 pf[2][2];
#pragma unroll
            for (int mt = 0; mt < 2; mt++) {
                pf[mt][0] = *(const bf16x8*)pf_p[mt][0];
                pf[mt][1] = *(const bf16x8*)pf_p[mt][1];
            }
#pragma unroll
            for (int nt = 0; nt < 4; nt++) {
                const bf16x8 vf0 = *(const bf16x8*)(vb_ + off_kv[nt][0]);
                const bf16x8 vf1 = *(const bf16x8*)(vb_ + off_kv[nt][1]);
#pragma unroll
                for (int mt = 0; mt < 2; mt++) {
                    acc_o[mt][nt] = MFMA16(pf[mt][0], vf0, acc_o[mt][nt]);
                    acc_o[mt][nt] = MFMA16(pf[mt][1], vf1, acc_o[mt][nt]);
                }
            }
        }
        if (kt < ktmax) {
            DRAIN(4);      // stage(kt+1) landed; stage(kt+2) in flight
            BARRIER();
        }
        cur = (cur == 2) ? 0 : cur + 1;
        nb  = (nb  == 2) ? 0 : nb  + 1;
    }
#undef STGKV

    // ---- epilogue: reduce l over the 16 lanes holding each row, normalize, store
#pragma unroll
    for (int mt = 0; mt < 2; mt++) {
#pragma unroll
        for (int rg = 0; rg < 4; rg++) {
            float rs = l_acc[mt][rg];
            rs += __shfl_xor(rs, 1);
            rs += __shfl_xor(rs, 2);
            rs += __shfl_xor(rs, 4);
            rs += __shfl_xor(rs, 8);
            const float inv = 1.0f / rs;
            const int s = qb * 128 + w * 32 + mt * 16 + quad * 4 + rg;
#pragma unroll
            for (int nt = 0; nt < 4; nt++) {
                const float val = acc_o[mt][nt][rg] * inv;
                y[((size_t)(b * SEQ + s)) * DM + h * HD + nt * 16 + l16] = (bf16)val;
            }
        }
    }
}

// ---------------------------------------------------------------- launch
extern "C" void kernel_launch(void* const* d_in, const int* in_sizes, int n_in,
                              void* d_out, int out_size, void* d_ws, size_t ws_size,
                              hipStream_t stream) {
    const float* x  = (const float*)d_in[0];
    const float* Wq = (const float*)d_in[1];
    const float* bq = (const float*)d_in[2];
    const float* Wk = (const float*)d_in[3];
    const float* bk = (const float*)d_in[4];
    const float* Wv = (const float*)d_in[5];
    const float* bv = (const float*)d_in[6];
    const float* Wo = (const float*)d_in[7];
    const float* bo = (const float*)d_in[8];

    // Workspace layout (88 MB total).
    char* ws = (char*)d_ws;
    bf16* xb   = (bf16*)(ws);                       // 16 MB: x bf16; reused as attn out y
    bf16* wall = (bf16*)(ws + (16ull << 20));       //  8 MB: Wq^T,Wk^T,Wv^T,Wo^T bf16
    bf16* qb   = (bf16*)(ws + (24ull << 20));       // 16 MB (q at +0, k at +TEN)
    bf16* kb   = (bf16*)(ws + (40ull << 20));       // 16 MB
    bf16* vtb  = (bf16*)(ws + (72ull << 20));       // 16 MB: V^T [B,H,D,S] (written by k_gemm<0> z=2)
    bf16* wot  = wall + 3ull * DM * DM;

    k_prep<<<dim3(16, 16, 5), 256, 0, stream>>>(x, Wq, Wk, Wv, Wo, wall, xb);
    k_gemm<0><<<dim3(32, 24), 512, 0, stream>>>(xb, wall, bq, bk, bv, vtb, qb);
    k_attn<<<dim3(64, 16), 256, 0, stream>>>(qb, kb, vtb, xb);
    k_gemm<1><<<dim3(32, 8), 512, 0, stream>>>(xb, wot, bo, bo, bo, vtb, d_out);
}

// Round 4
// 242.007 us; speedup vs baseline: 1.0624x; 1.0361x over previous
//
#include <hip/hip_runtime.h>

typedef __bf16 bf16;
typedef __bf16 bf16x2 __attribute__((ext_vector_type(2)));
typedef __bf16 bf16x4 __attribute__((ext_vector_type(4)));
typedef __bf16 bf16x8 __attribute__((ext_vector_type(8)));
typedef float  f32x4  __attribute__((ext_vector_type(4)));

#define MFMA16(a,b,c) __builtin_amdgcn_mfma_f32_16x16x32_bf16(a,b,c,0,0,0)
// async global->LDS DMA, 16B per lane; LDS dest is wave-uniform base + lane*16
#define GLL16(g, l) __builtin_amdgcn_global_load_lds( \
    (const __attribute__((address_space(1))) unsigned char*)(g), \
    (__attribute__((address_space(3))) unsigned char*)(l), 16, 0, 0)
#define BARRIER() asm volatile("s_barrier" ::: "memory")
#define DRAIN(n)  asm volatile("s_waitcnt vmcnt(" #n ")" ::: "memory")

constexpr int SEQ   = 2048;
constexpr int NH    = 16;
constexpr int HD    = 64;
constexpr int BATCH = 4;
constexpr int DM    = 1024;          // model dim
constexpr size_t TEN = (size_t)BATCH * NH * SEQ * HD;   // 8,388,608 elems per tensor

// ---------------------------------------------------------------- prep: weight transpose (z=0..3) + x convert (z=4)
__global__ __launch_bounds__(256) void k_prep(const float* __restrict__ x,
                                              const float* __restrict__ W0,
                                              const float* __restrict__ W1,
                                              const float* __restrict__ W2,
                                              const float* __restrict__ W3,
                                              bf16* __restrict__ Wt_all,
                                              bf16* __restrict__ xb) {
    __shared__ float T[64][65];
    const int z = blockIdx.z;
    const int t = threadIdx.x;
    if (z == 4) {
        // convert x (fp32 -> bf16): 256 blocks x 256 threads x 128 elems
        const int bi = blockIdx.y * 16 + blockIdx.x;
#pragma unroll
        for (int c = 0; c < 16; c++) {
            const size_t idx = (size_t)c * 524288 + ((size_t)bi * 256 + t) * 8;
            float4 f0 = *(const float4*)(x + idx);
            float4 f1 = *(const float4*)(x + idx + 4);
            bf16x8 o;
            o[0] = (bf16)f0.x; o[1] = (bf16)f0.y; o[2] = (bf16)f0.z; o[3] = (bf16)f0.w;
            o[4] = (bf16)f1.x; o[5] = (bf16)f1.y; o[6] = (bf16)f1.z; o[7] = (bf16)f1.w;
            *(bf16x8*)(xb + idx) = o;
        }
        return;
    }
    const float* W = (z == 0) ? W0 : (z == 1) ? W1 : (z == 2) ? W2 : W3;
    bf16* Wt = Wt_all + (size_t)z * DM * DM;
    const int kb = blockIdx.x, nb = blockIdx.y;
    const int rl = t >> 2, seg = t & 3;
    const float* src = W + (size_t)(kb * 64 + rl) * DM + nb * 64 + seg * 16;
#pragma unroll
    for (int j4 = 0; j4 < 4; j4++) {
        float4 f = *(const float4*)(src + j4 * 4);
        T[rl][seg * 16 + j4 * 4 + 0] = f.x;
        T[rl][seg * 16 + j4 * 4 + 1] = f.y;
        T[rl][seg * 16 + j4 * 4 + 2] = f.z;
        T[rl][seg * 16 + j4 * 4 + 3] = f.w;
    }
    __syncthreads();
    bf16* dst = Wt + (size_t)(nb * 64 + rl) * DM + kb * 64 + seg * 16;
    bf16x8 o0, o1;
#pragma unroll
    for (int j = 0; j < 8; j++) {
        o0[j] = (bf16)T[seg * 16 + j][rl];
        o1[j] = (bf16)T[seg * 16 + 8 + j][rl];
    }
    *(bf16x8*)dst = o0;
    *(bf16x8*)(dst + 8) = o1;
}

// ---------------------------------------------------------------- GEMM: 256x128 tile, BK=64, 4-phase/iter pipeline
// (unchanged from round 3 — measured best at 70.4 µs; LDS-BW model says all
// schedule variants cap at ~30% machine MfmaUtil for this geometry, so this
// kernel is parked.)
// Geometry: MODE0 grid 32x24 = 768 blocks = exactly 3 rounds at 1 block/CU;
// MODE1 grid 32x8 = 256 = exactly 1 round. 512 threads = 8 waves, 2M x 4N;
// per-wave C = 128x32 = acc[8][2]. LDS 128 KB: A triple-buffered (3 x 32 KB),
// B double-buffered (2 x 16 KB). XOR swizzle seg' = seg ^ (row&7)
// (bank-conflict-0 verified). Counted DRAIN(6), never vmcnt(0) in loop;
// setprio around MFMA. K order ascending -> bit-identical accumulation.
template <int MODE>
__global__ __launch_bounds__(512, 1) void k_gemm(const bf16* __restrict__ A,
                                                 const bf16* __restrict__ Wt0,
                                                 const float* __restrict__ b0,
                                                 const float* __restrict__ b1,
                                                 const float* __restrict__ b2,
                                                 bf16* __restrict__ vt,
                                                 void* __restrict__ out) {
    __shared__ __align__(1024) bf16 LA[3][16384];   // 96 KB
    __shared__ __align__(1024) bf16 LB[2][8192];    // 32 KB
    const int t = threadIdx.x;
    const int w = t >> 6, lane = t & 63, quad = lane >> 4, l16 = lane & 15;
    const int bm = blockIdx.x * 256;
    const int by = blockIdx.y;
    const int z  = (MODE == 0) ? (by >> 3) : 0;
    const int bn = (MODE == 0) ? ((by & 7) * 128) : (by * 128);
    const bf16* Wt = Wt0 + (size_t)z * DM * DM;
    const float* bias = (z == 0) ? b0 : (z == 1) ? b1 : b2;
    const int wm = (w >> 2) * 128, wn = (w & 3) * 32;

    // staging lane mapping: chunk = 8 rows x 64 cols (1 KB); lane -> (row, seg)
    const int srow = lane >> 3;
    const int sseg = (lane & 7) ^ srow;               // global seg (de-swizzled)
    const bf16* gA = A  + (size_t)(bm + w * 8 + srow) * DM + sseg * 8;
    const bf16* gB = Wt + (size_t)(bn + w * 8 + srow) * DM + sseg * 8;

// A-tile = 32 chunks; call c stages chunks c*16+w, c*16+w+8 (rows c*128+w*8 +{0,64})
#define STGA_P(lp, tt, c) do { \
    const bf16* _g = gA + (size_t)(c) * 128 * DM + (size_t)(tt) * 64; \
    bf16* _l = (lp) + ((c) * 16 + w) * 512; \
    GLL16(_g, _l); GLL16(_g + 64 * DM, _l + 4096); \
} while (0)
// B-tile = 16 chunks; wave stages chunks w, w+8
#define STGB_P(lp, tt) do { \
    const bf16* _g = gB + (size_t)(tt) * 64; \
    bf16* _l = (lp) + w * 512; \
    GLL16(_g, _l); GLL16(_g + 64 * DM, _l + 4096); \
} while (0)

    // fragment read swizzled seg offsets (elements): seg k-slice 0 / 1
    const int sA0 = (quad ^ (l16 & 7)) << 3;
    const int sA1 = ((4 + quad) ^ (l16 & 7)) << 3;

    f32x4 zero = {0.f, 0.f, 0.f, 0.f};
    f32x4 acc[8][2];
#pragma unroll
    for (int mt = 0; mt < 8; mt++)
#pragma unroll
        for (int nt = 0; nt < 2; nt++) acc[mt][nt] = zero;
    bf16x8 bfr[2][2];

#define PH(la_, lb_, mb, READB, STAGE_STMT, DRAIN_STMT) do { \
    const bf16* _la = (la_); \
    if (READB) { \
        const bf16* _lb = (lb_); \
        _Pragma("unroll") \
        for (int nt = 0; nt < 2; nt++) { \
            const int r = (wn + nt * 16 + l16) * 64; \
            bfr[nt][0] = *(const bf16x8*)(_lb + r + sA0); \
            bfr[nt][1] = *(const bf16x8*)(_lb + r + sA1); \
        } \
    } \
    bf16x8 af[4][2]; \
    _Pragma("unroll") \
    for (int mi = 0; mi < 4; mi++) { \
        const int r = (wm + ((mb) + mi) * 16 + l16) * 64; \
        af[mi][0] = *(const bf16x8*)(_la + r + sA0); \
        af[mi][1] = *(const bf16x8*)(_la + r + sA1); \
    } \
    STAGE_STMT; \
    DRAIN_STMT; \
    BARRIER(); \
    __builtin_amdgcn_s_setprio(1); \
    _Pragma("unroll") \
    for (int mi = 0; mi < 4; mi++) \
        _Pragma("unroll") \
        for (int nt = 0; nt < 2; nt++) { \
            f32x4 a = acc[(mb) + mi][nt]; \
            a = MFMA16(af[mi][0], bfr[nt][0], a); \
            a = MFMA16(af[mi][1], bfr[nt][1], a); \
            acc[(mb) + mi][nt] = a; \
        } \
    __builtin_amdgcn_s_setprio(0); \
    BARRIER(); \
} while (0)

    // prologue: A(T0),B(T0),A(T1),B(T1) in flight; complete first 6 (=T0)
    STGA_P(&LA[0][0], 0, 0); STGA_P(&LA[0][0], 0, 1); STGB_P(&LB[0][0], 0);
    STGA_P(&LA[1][0], 1, 0); STGA_P(&LA[1][0], 1, 1); STGB_P(&LB[1][0], 1);
    DRAIN(6);
    BARRIER();

    int ae = 0, ao = 1, an = 2;
    for (int i = 0; i < 8; i++) {
        const int tE = (i < 7) ? 2 * i + 2 : 15;   // clamp: restage L2-hot T15
        const int tO = (i < 7) ? 2 * i + 3 : 15;
        bf16* lae = &LA[0][0] + ae * 16384;
        bf16* lao = &LA[0][0] + ao * 16384;
        bf16* lan = &LA[0][0] + an * 16384;
        PH(lae, &LB[0][0], 0, 1, { STGA_P(lan, tE, 0); STGA_P(lan, tE, 1); }, );
        PH(lae, (const bf16*)0, 4, 0, STGB_P(&LB[0][0], tE), DRAIN(6));
        PH(lao, &LB[1][0], 0, 1, { STGA_P(lae, tO, 0); STGA_P(lae, tO, 1); }, );
        PH(lao, (const bf16*)0, 4, 0, STGB_P(&LB[1][0], tO), DRAIN(6));
        const int tmp = ae; ae = an; an = ao; ao = tmp;
    }
#undef PH
#undef STGA_P
#undef STGB_P

    // ---------------- epilogue
    float bv[2], invf[2];
#pragma unroll
    for (int nt = 0; nt < 2; nt++) {
        const int col = bn + wn + nt * 16 + l16;
        bv[nt] = bias[col];
        if (MODE == 0) {
            const int ip = (col & 63) >> 1;   // rope pair index: 10000^(-ip/32)
            invf[nt] = __builtin_exp2f(-0.41524101186092029f * (float)ip);
        }
    }
    const int odd = l16 & 1;

    if (MODE == 0 && z == 2) {
        // V: store transposed to vt [B,H,D,S]; 4 consecutive s per lane -> bf16x4
#pragma unroll
        for (int mt = 0; mt < 8; mt++) {
            const int row0 = bm + wm + mt * 16 + quad * 4;
            const int b = row0 >> 11, s0 = row0 & (SEQ - 1);
#pragma unroll
            for (int nt = 0; nt < 2; nt++) {
                const int col = bn + wn + nt * 16 + l16;
                const int h = col >> 6, dd = col & 63;
                bf16x4 o;
#pragma unroll
                for (int rg = 0; rg < 4; rg++) o[rg] = (bf16)(acc[mt][nt][rg] + bv[nt]);
                *(bf16x4*)(vt + ((size_t)((b * NH + h) * HD + dd)) * SEQ + s0) = o;
            }
        }
        return;
    }

#pragma unroll
    for (int mt = 0; mt < 8; mt++) {
#pragma unroll
        for (int nt = 0; nt < 2; nt++) {
            const int col = bn + wn + nt * 16 + l16;
#pragma unroll
            for (int rg = 0; rg < 4; rg++) {
                const int row = bm + wm + mt * 16 + quad * 4 + rg;
                float val = acc[mt][nt][rg] + bv[nt];
                if (MODE == 0) {
                    const int b = row >> 11, s = row & (SEQ - 1);
                    const int h = col >> 6, dd = col & 63;
                    // fused RoPE on q,k (q pre-scaled 1/8); partner (col^1) is in
                    // lane l16^1, same regs -> shfl_xor(1)
                    const float partner = __shfl_xor(val, 1);
                    float sn, cs;
                    __sincosf((float)s * invf[nt], &sn, &cs);
                    val = odd ? (val * cs + partner * sn)
                              : (val * cs - partner * sn);
                    if (z == 0) val *= 0.125f;
                    ((bf16*)out)[(size_t)z * TEN +
                                 (((size_t)(b * NH + h)) * SEQ + s) * HD + dd] = (bf16)val;
                } else {
                    ((float*)out)[(size_t)row * DM + col] = val;
                }
            }
        }
    }
}

// ---------------------------------------------------------------- flash attention (causal)
// grid: (bh=64, 16). qb = 15 - blockIdx.y (heavy-first). One 128-row q-block per block.
// THIS ROUND (single-variable experiment): 3 blocks/CU instead of 2.
//  - K/V double-buffered (2 x 8 KB each) + 16 KB P => 48 KB LDS -> 3 blocks/CU.
//  - __launch_bounds__(256,3): VGPR cap 170 >> kernel's ~100, no spill risk
//    (the (256,4) -> 64-VGPR spill disaster from the earlier session is avoided).
//  - per-tile schedule: compute(cur) -> BARRIER (cur's readers done) ->
//    STGKV(cur, t+2) -> DRAIN(4) (own S_{t+1} complete; FIFO queue is
//    [S_{t+1}(4), S_{t+2}(4)]) -> BARRIER (all waves' S_{t+1} published).
//    2 barriers/tile vs round-3's 1, but +50% cross-block TLP covers it.
//  - s_setprio(1/0) around both MFMA clusters (T5: measured +4-7% attn, m191).
// Arithmetic order unchanged -> bit-identical output.
__global__ __launch_bounds__(256, 3) void k_attn(const bf16* __restrict__ q,
                                                 const bf16* __restrict__ k,
                                                 const bf16* __restrict__ vt,
                                                 bf16* __restrict__ y) {
    __shared__ __align__(1024) bf16 KsF[2][4096];      // 2 x 8 KB [kv][d] swizzled
    __shared__ __align__(1024) bf16 VsF[2][4096];      // 2 x 8 KB [d][kv] swizzled
    __shared__ __align__(1024) bf16 PsF[4 * 32 * 64];  // 16 KB per-wave P scratch, swizzled
    const int t = threadIdx.x;
    const int w = t >> 6, lane = t & 63, quad = lane >> 4, l16 = lane & 15;
    const int bh = blockIdx.x;                // bh fastest => qb-blocks of one bh share an XCD
    const int qb = 15 - (int)blockIdx.y;      // heavy blocks dispatch first
    const int b = bh >> 4, h = bh & 15;

    const int srow = lane >> 3;                       // row within chunk
    const int gseg = (lane & 7) ^ srow;               // global seg fetched (de-swizzle)
    const int c0 = w, c1 = w + 4;                     // this wave's chunks

    const bf16* kbase = k  + (size_t)bh * SEQ * HD;
    const bf16* vbase = vt + (size_t)bh * HD * SEQ;
    const float NEG_INF = -__builtin_inff();

    const int koff0 = (c0 * 8 + srow) * HD + gseg * 8;
    const int koff1 = (c1 * 8 + srow) * HD + gseg * 8;
    const int voff0 = (c0 * 8 + srow) * SEQ + gseg * 8;
    const int voff1 = (c1 * 8 + srow) * SEQ + gseg * 8;

#define STGKV(buf, tt) do { \
    GLL16(kbase + (size_t)(tt) * 64 * HD + koff0, &KsF[buf][c0 * 512]); \
    GLL16(kbase + (size_t)(tt) * 64 * HD + koff1, &KsF[buf][c1 * 512]); \
    GLL16(vbase + (size_t)(tt) * 64 + voff0, &VsF[buf][c0 * 512]); \
    GLL16(vbase + (size_t)(tt) * 64 + voff1, &VsF[buf][c1 * 512]); \
} while (0)

    // Q fragments: 2 m-tiles, A-layout (issued before the staging DMAs, so the
    // prologue DRAIN(4) counts [Q(4), S0(4), S1(4)] and completes Q+S0)
    bf16x8 qf[2][2];
#pragma unroll
    for (int mt = 0; mt < 2; mt++) {
        const bf16* qrow = q + ((size_t)bh * SEQ + qb * 128 + w * 32 + mt * 16 + l16) * HD;
        qf[mt][0] = *(const bf16x8*)(qrow + quad * 8);
        qf[mt][1] = *(const bf16x8*)(qrow + 32 + quad * 8);
    }

    const int ktmax = 2 * qb + 1;
    STGKV(0, 0);
    STGKV(1, 1);

    int off_kv[4][2];
#pragma unroll
    for (int nt = 0; nt < 4; nt++) {
        const int r = nt * 16 + l16;
#pragma unroll
        for (int hh = 0; hh < 2; hh++) {
            const int sg = hh * 4 + quad;
            off_kv[nt][hh] = r * 64 + ((sg ^ (r & 7)) << 3);
        }
    }
    const bf16 *pf_p[2][2];
#pragma unroll
    for (int mt = 0; mt < 2; mt++) {
        const int r = mt * 16 + l16;
#pragma unroll
        for (int hh = 0; hh < 2; hh++) {
            const int sg = hh * 4 + quad;
            pf_p[mt][hh] = PsF + w * 2048 + r * 64 + ((sg ^ (r & 7)) << 3);
        }
    }

    f32x4 zero = {0.f, 0.f, 0.f, 0.f};
    f32x4 minus10 = {-10.f, -10.f, -10.f, -10.f};
    f32x4 acc_o[2][4];
    float l_acc[2][4];
#pragma unroll
    for (int mt = 0; mt < 2; mt++)
#pragma unroll
        for (int nt = 0; nt < 4; nt++) acc_o[mt][nt] = zero;
#pragma unroll
    for (int mt = 0; mt < 2; mt++)
#pragma unroll
        for (int rg = 0; rg < 4; rg++) l_acc[mt][rg] = 0.f;

    DRAIN(4);      // Q + tile 0 landed (tile 1 in flight)
    BARRIER();

    for (int kt = 0; kt <= ktmax; kt++) {
        const int cur = kt & 1;
        const bf16* kb_ = &KsF[0][0] + cur * 4096;
        const bf16* vb_ = &VsF[0][0] + cur * 4096;

        const int d = qb * 128 + w * 32 - kt * 64;   // wave-row offset vs kv base
        if (d > -32) {                      // else fully masked: skip (wave-uniform)
            // ---- S = Q K^T - 10
            f32x4 accs[2][4];
            __builtin_amdgcn_s_setprio(1);
#pragma unroll
            for (int nt = 0; nt < 4; nt++) {
                const bf16x8 kf0 = *(const bf16x8*)(kb_ + off_kv[nt][0]);
                const bf16x8 kf1 = *(const bf16x8*)(kb_ + off_kv[nt][1]);
#pragma unroll
                for (int mt = 0; mt < 2; mt++) {
                    f32x4 a = minus10;
                    a = MFMA16(qf[mt][0], kf0, a);
                    a = MFMA16(qf[mt][1], kf1, a);
                    accs[mt][nt] = a;
                }
            }
            __builtin_amdgcn_s_setprio(0);
            // ---- causal mask (only when the 64-kv tile straddles this wave's rows)
            if (d < 64) {
#pragma unroll
                for (int mt = 0; mt < 2; mt++) {
                    const int qr = d + mt * 16 + quad * 4;
#pragma unroll
                    for (int nt = 0; nt < 4; nt++) {
                        const int kv = nt * 16 + l16;
#pragma unroll
                        for (int rg = 0; rg < 4; rg++)
                            if (kv > qr + rg) accs[mt][nt][rg] = NEG_INF;
                    }
                }
            }
            // ---- p = exp(S-10); per-lane row-sum; P -> swizzled wave-private LDS
#pragma unroll
            for (int mt = 0; mt < 2; mt++) {
#pragma unroll
                for (int nt = 0; nt < 4; nt++) {
#pragma unroll
                    for (int rg = 0; rg < 4; rg++) {
                        const float p = __expf(accs[mt][nt][rg]);
                        l_acc[mt][rg] += p;
                        const int prow = mt * 16 + quad * 4 + rg;
                        const int psg  = (nt * 2 + (l16 >> 3)) ^ (prow & 7);
                        PsF[w * 2048 + prow * 64 + psg * 8 + (l16 & 7)] = (bf16)p;
                    }
                }
            }
            // ---- O += P V (in-order DS pipe: no barrier for wave-private P)
            bf16x8 pf[2][2];
#pragma unroll
            for (int mt = 0; mt < 2; mt++) {
                pf[mt][0] = *(const bf16x8*)pf_p[mt][0];
                pf[mt][1] = *(const bf16x8*)pf_p[mt][1];
            }
            __builtin_amdgcn_s_setprio(1);
#pragma unroll
            for (int nt = 0; nt < 4; nt++) {
                const bf16x8 vf0 = *(const bf16x8*)(vb_ + off_kv[nt][0]);
                const bf16x8 vf1 = *(const bf16x8*)(vb_ + off_kv[nt][1]);
#pragma unroll
                for (int mt = 0; mt < 2; mt++) {
                    acc_o[mt][nt] = MFMA16(pf[mt][0], vf0, acc_o[mt][nt]);
                    acc_o[mt][nt] = MFMA16(pf[mt][1], vf1, acc_o[mt][nt]);
                }
            }
            __builtin_amdgcn_s_setprio(0);
        }
        if (kt < ktmax) {
            BARRIER();                                   // buf cur's readers done
            const int ts = (kt + 2 > ktmax) ? ktmax : (kt + 2);  // clamp: restage hot tile
            STGKV(cur, ts);                              // refill freed buffer
            DRAIN(4);                                    // own S_{kt+1} complete
            BARRIER();                                   // all waves' S_{kt+1} published
        }
    }
#undef STGKV

    // ---- epilogue: reduce l over the 16 lanes holding each row, normalize, store
#pragma unroll
    for (int mt = 0; mt < 2; mt++) {
#pragma unroll
        for (int rg = 0; rg < 4; rg++) {
            float rs = l_acc[mt][rg];
            rs += __shfl_xor(rs, 1);
            rs += __shfl_xor(rs, 2);
            rs += __shfl_xor(rs, 4);
            rs += __shfl_xor(rs, 8);
            const float inv = 1.0f / rs;
            const int s = qb * 128 + w * 32 + mt * 16 + quad * 4 + rg;
#pragma unroll
            for (int nt = 0; nt < 4; nt++) {
                const float val = acc_o[mt][nt][rg] * inv;
                y[((size_t)(b * SEQ + s)) * DM + h * HD + nt * 16 + l16] = (bf16)val;
            }
        }
    }
}

// ---------------------------------------------------------------- launch
extern "C" void kernel_launch(void* const* d_in, const int* in_sizes, int n_in,
                              void* d_out, int out_size, void* d_ws, size_t ws_size,
                              hipStream_t stream) {
    const float* x  = (const float*)d_in[0];
    const float* Wq = (const float*)d_in[1];
    const float* bq = (const float*)d_in[2];
    const float* Wk = (const float*)d_in[3];
    const float* bk = (const float*)d_in[4];
    const float* Wv = (const float*)d_in[5];
    const float* bv = (const float*)d_in[6];
    const float* Wo = (const float*)d_in[7];
    const float* bo = (const float*)d_in[8];

    // Workspace layout (88 MB total).
    char* ws = (char*)d_ws;
    bf16* xb   = (bf16*)(ws);                       // 16 MB: x bf16; reused as attn out y
    bf16* wall = (bf16*)(ws + (16ull << 20));       //  8 MB: Wq^T,Wk^T,Wv^T,Wo^T bf16
    bf16* qb   = (bf16*)(ws + (24ull << 20));       // 16 MB (q at +0, k at +TEN)
    bf16* kb   = (bf16*)(ws + (40ull << 20));       // 16 MB
    bf16* vtb  = (bf16*)(ws + (72ull << 20));       // 16 MB: V^T [B,H,D,S] (written by k_gemm<0> z=2)
    bf16* wot  = wall + 3ull * DM * DM;

    k_prep<<<dim3(16, 16, 5), 256, 0, stream>>>(x, Wq, Wk, Wv, Wo, wall, xb);
    k_gemm<0><<<dim3(32, 24), 512, 0, stream>>>(xb, wall, bq, bk, bv, vtb, qb);
    k_attn<<<dim3(64, 16), 256, 0, stream>>>(qb, kb, vtb, xb);
    k_gemm<1><<<dim3(32, 8), 512, 0, stream>>>(xb, wot, bo, bo, bo, vtb, d_out);
}

// Round 5
// 239.402 us; speedup vs baseline: 1.0740x; 1.0109x over previous
//
#include <hip/hip_runtime.h>

typedef __bf16 bf16;
typedef __bf16 bf16x2 __attribute__((ext_vector_type(2)));
typedef __bf16 bf16x4 __attribute__((ext_vector_type(4)));
typedef __bf16 bf16x8 __attribute__((ext_vector_type(8)));
typedef float  f32x4  __attribute__((ext_vector_type(4)));

#define MFMA16(a,b,c) __builtin_amdgcn_mfma_f32_16x16x32_bf16(a,b,c,0,0,0)
// async global->LDS DMA, 16B per lane; LDS dest is wave-uniform base + lane*16
#define GLL16(g, l) __builtin_amdgcn_global_load_lds( \
    (const __attribute__((address_space(1))) unsigned char*)(g), \
    (__attribute__((address_space(3))) unsigned char*)(l), 16, 0, 0)
#define BARRIER() asm volatile("s_barrier" ::: "memory")
#define DRAIN(n)  asm volatile("s_waitcnt vmcnt(" #n ")" ::: "memory")

constexpr int SEQ   = 2048;
constexpr int NH    = 16;
constexpr int HD    = 64;
constexpr int BATCH = 4;
constexpr int DM    = 1024;          // model dim
constexpr size_t TEN = (size_t)BATCH * NH * SEQ * HD;   // 8,388,608 elems per tensor

// ---------------------------------------------------------------- prep: weight transpose (z=0..3) + x convert (z=4)
__global__ __launch_bounds__(256) void k_prep(const float* __restrict__ x,
                                              const float* __restrict__ W0,
                                              const float* __restrict__ W1,
                                              const float* __restrict__ W2,
                                              const float* __restrict__ W3,
                                              bf16* __restrict__ Wt_all,
                                              bf16* __restrict__ xb) {
    __shared__ float T[64][65];
    const int z = blockIdx.z;
    const int t = threadIdx.x;
    if (z == 4) {
        // convert x (fp32 -> bf16): 256 blocks x 256 threads x 128 elems
        const int bi = blockIdx.y * 16 + blockIdx.x;
#pragma unroll
        for (int c = 0; c < 16; c++) {
            const size_t idx = (size_t)c * 524288 + ((size_t)bi * 256 + t) * 8;
            float4 f0 = *(const float4*)(x + idx);
            float4 f1 = *(const float4*)(x + idx + 4);
            bf16x8 o;
            o[0] = (bf16)f0.x; o[1] = (bf16)f0.y; o[2] = (bf16)f0.z; o[3] = (bf16)f0.w;
            o[4] = (bf16)f1.x; o[5] = (bf16)f1.y; o[6] = (bf16)f1.z; o[7] = (bf16)f1.w;
            *(bf16x8*)(xb + idx) = o;
        }
        return;
    }
    const float* W = (z == 0) ? W0 : (z == 1) ? W1 : (z == 2) ? W2 : W3;
    bf16* Wt = Wt_all + (size_t)z * DM * DM;
    const int kb = blockIdx.x, nb = blockIdx.y;
    const int rl = t >> 2, seg = t & 3;
    const float* src = W + (size_t)(kb * 64 + rl) * DM + nb * 64 + seg * 16;
#pragma unroll
    for (int j4 = 0; j4 < 4; j4++) {
        float4 f = *(const float4*)(src + j4 * 4);
        T[rl][seg * 16 + j4 * 4 + 0] = f.x;
        T[rl][seg * 16 + j4 * 4 + 1] = f.y;
        T[rl][seg * 16 + j4 * 4 + 2] = f.z;
        T[rl][seg * 16 + j4 * 4 + 3] = f.w;
    }
    __syncthreads();
    bf16* dst = Wt + (size_t)(nb * 64 + rl) * DM + kb * 64 + seg * 16;
    bf16x8 o0, o1;
#pragma unroll
    for (int j = 0; j < 8; j++) {
        o0[j] = (bf16)T[seg * 16 + j][rl];
        o1[j] = (bf16)T[seg * 16 + 8 + j][rl];
    }
    *(bf16x8*)dst = o0;
    *(bf16x8*)(dst + 8) = o1;
}

// ---------------------------------------------------------------- GEMM: 256x128 tile, BK=64, 4-phase/iter pipeline
// ROUND-5 CHANGE (single variable): wave grid 2m x 4n -> 4m x 2n, i.e. per-wave
// output 128x32 -> 64x64. LDS-BW model (validated: predicts m201's 62% and
// round-3's ~30% MfmaUtil): util ~ MFMA-cyc / LDS-cyc; per-wave 64x64 reads
// 16 KB per 524 kFLOP vs 128x32's 20 KB -> block LDS traffic 208->176 KB per
// K64 tile, model util 38% -> 45%. acc[4][4]=64 VGPR.
// Everything else byte-identical to round 3 (measured best): zero-tail grids
// (MODE0 768 = 3 rounds, MODE1 256 = 1 round), A triple / B double buffered,
// XOR swizzle seg'=seg^(row&7) (bank-conflict-0 verified), counted DRAIN(6)
// (never vmcnt(0) in loop), setprio around MFMA, K ascending -> bit-identical.
template <int MODE>
__global__ __launch_bounds__(512, 1) void k_gemm(const bf16* __restrict__ A,
                                                 const bf16* __restrict__ Wt0,
                                                 const float* __restrict__ b0,
                                                 const float* __restrict__ b1,
                                                 const float* __restrict__ b2,
                                                 bf16* __restrict__ vt,
                                                 void* __restrict__ out) {
    __shared__ __align__(1024) bf16 LA[3][16384];   // 96 KB
    __shared__ __align__(1024) bf16 LB[2][8192];    // 32 KB
    const int t = threadIdx.x;
    const int w = t >> 6, lane = t & 63, quad = lane >> 4, l16 = lane & 15;
    const int bm = blockIdx.x * 256;
    const int by = blockIdx.y;
    const int z  = (MODE == 0) ? (by >> 3) : 0;
    const int bn = (MODE == 0) ? ((by & 7) * 128) : (by * 128);
    const bf16* Wt = Wt0 + (size_t)z * DM * DM;
    const float* bias = (z == 0) ? b0 : (z == 1) ? b1 : b2;
    const int wm = (w >> 1) * 64, wn = (w & 1) * 64;   // 4m x 2n wave grid

    // staging lane mapping: chunk = 8 rows x 64 cols (1 KB); lane -> (row, seg)
    const int srow = lane >> 3;
    const int sseg = (lane & 7) ^ srow;               // global seg (de-swizzled)
    const bf16* gA = A  + (size_t)(bm + w * 8 + srow) * DM + sseg * 8;
    const bf16* gB = Wt + (size_t)(bn + w * 8 + srow) * DM + sseg * 8;

// A-tile = 32 chunks; call c stages chunks c*16+w, c*16+w+8 (rows c*128+w*8 +{0,64})
#define STGA_P(lp, tt, c) do { \
    const bf16* _g = gA + (size_t)(c) * 128 * DM + (size_t)(tt) * 64; \
    bf16* _l = (lp) + ((c) * 16 + w) * 512; \
    GLL16(_g, _l); GLL16(_g + 64 * DM, _l + 4096); \
} while (0)
// B-tile = 16 chunks; wave stages chunks w, w+8
#define STGB_P(lp, tt) do { \
    const bf16* _g = gB + (size_t)(tt) * 64; \
    bf16* _l = (lp) + w * 512; \
    GLL16(_g, _l); GLL16(_g + 64 * DM, _l + 4096); \
} while (0)

    // fragment read swizzled seg offsets (elements): seg k-slice 0 / 1
    const int sA0 = (quad ^ (l16 & 7)) << 3;
    const int sA1 = ((4 + quad) ^ (l16 & 7)) << 3;

    f32x4 zero = {0.f, 0.f, 0.f, 0.f};
    f32x4 acc[4][4];
#pragma unroll
    for (int mt = 0; mt < 4; mt++)
#pragma unroll
        for (int nt = 0; nt < 4; nt++) acc[mt][nt] = zero;
    bf16x8 bfr[4][2];    // full per-wave B (64 cols x K64), read once per K-tile

// Phase: computes m-subtiles {mb, mb+1} x all 4 n-subtiles x K64 = 16 MFMA.
// READB phases additionally load the K-tile's 8 B-fragments (held 2 phases).
#define PH(la_, lb_, mb, READB, STAGE_STMT, DRAIN_STMT) do { \
    const bf16* _la = (la_); \
    if (READB) { \
        const bf16* _lb = (lb_); \
        _Pragma("unroll") \
        for (int nt = 0; nt < 4; nt++) { \
            const int r = (wn + nt * 16 + l16) * 64; \
            bfr[nt][0] = *(const bf16x8*)(_lb + r + sA0); \
            bfr[nt][1] = *(const bf16x8*)(_lb + r + sA1); \
        } \
    } \
    bf16x8 af[2][2]; \
    _Pragma("unroll") \
    for (int mi = 0; mi < 2; mi++) { \
        const int r = (wm + ((mb) + mi) * 16 + l16) * 64; \
        af[mi][0] = *(const bf16x8*)(_la + r + sA0); \
        af[mi][1] = *(const bf16x8*)(_la + r + sA1); \
    } \
    STAGE_STMT; \
    DRAIN_STMT; \
    BARRIER(); \
    __builtin_amdgcn_s_setprio(1); \
    _Pragma("unroll") \
    for (int mi = 0; mi < 2; mi++) \
        _Pragma("unroll") \
        for (int nt = 0; nt < 4; nt++) { \
            f32x4 a = acc[(mb) + mi][nt]; \
            a = MFMA16(af[mi][0], bfr[nt][0], a); \
            a = MFMA16(af[mi][1], bfr[nt][1], a); \
            acc[(mb) + mi][nt] = a; \
        } \
    __builtin_amdgcn_s_setprio(0); \
    BARRIER(); \
} while (0)

    // prologue: A(T0),B(T0),A(T1),B(T1) in flight; complete first 6 (=T0)
    STGA_P(&LA[0][0], 0, 0); STGA_P(&LA[0][0], 0, 1); STGB_P(&LB[0][0], 0);
    STGA_P(&LA[1][0], 1, 0); STGA_P(&LA[1][0], 1, 1); STGB_P(&LB[1][0], 1);
    DRAIN(6);
    BARRIER();

    int ae = 0, ao = 1, an = 2;
    for (int i = 0; i < 8; i++) {
        const int tE = (i < 7) ? 2 * i + 2 : 15;   // clamp: restage L2-hot T15
        const int tO = (i < 7) ? 2 * i + 3 : 15;
        bf16* lae = &LA[0][0] + ae * 16384;
        bf16* lao = &LA[0][0] + ao * 16384;
        bf16* lan = &LA[0][0] + an * 16384;
        PH(lae, &LB[0][0], 0, 1, { STGA_P(lan, tE, 0); STGA_P(lan, tE, 1); }, );
        PH(lae, (const bf16*)0, 2, 0, STGB_P(&LB[0][0], tE), DRAIN(6));
        PH(lao, &LB[1][0], 0, 1, { STGA_P(lae, tO, 0); STGA_P(lae, tO, 1); }, );
        PH(lao, (const bf16*)0, 2, 0, STGB_P(&LB[1][0], tO), DRAIN(6));
        const int tmp = ae; ae = an; an = ao; ao = tmp;
    }
#undef PH
#undef STGA_P
#undef STGB_P

    // ---------------- epilogue (per-wave 64x64: mt,nt in 0..3)
    float bv[4], invf[4];
#pragma unroll
    for (int nt = 0; nt < 4; nt++) {
        const int col = bn + wn + nt * 16 + l16;
        bv[nt] = bias[col];
        if (MODE == 0) {
            const int ip = (col & 63) >> 1;   // rope pair index: 10000^(-ip/32)
            invf[nt] = __builtin_exp2f(-0.41524101186092029f * (float)ip);
        }
    }
    const int odd = l16 & 1;

    if (MODE == 0 && z == 2) {
        // V: store transposed to vt [B,H,D,S]; 4 consecutive s per lane -> bf16x4
#pragma unroll
        for (int mt = 0; mt < 4; mt++) {
            const int row0 = bm + wm + mt * 16 + quad * 4;
            const int b = row0 >> 11, s0 = row0 & (SEQ - 1);
#pragma unroll
            for (int nt = 0; nt < 4; nt++) {
                const int col = bn + wn + nt * 16 + l16;
                const int h = col >> 6, dd = col & 63;
                bf16x4 o;
#pragma unroll
                for (int rg = 0; rg < 4; rg++) o[rg] = (bf16)(acc[mt][nt][rg] + bv[nt]);
                *(bf16x4*)(vt + ((size_t)((b * NH + h) * HD + dd)) * SEQ + s0) = o;
            }
        }
        return;
    }

#pragma unroll
    for (int mt = 0; mt < 4; mt++) {
#pragma unroll
        for (int nt = 0; nt < 4; nt++) {
            const int col = bn + wn + nt * 16 + l16;
#pragma unroll
            for (int rg = 0; rg < 4; rg++) {
                const int row = bm + wm + mt * 16 + quad * 4 + rg;
                float val = acc[mt][nt][rg] + bv[nt];
                if (MODE == 0) {
                    const int b = row >> 11, s = row & (SEQ - 1);
                    const int h = col >> 6, dd = col & 63;
                    // fused RoPE on q,k (q pre-scaled 1/8); partner (col^1) is in
                    // lane l16^1, same regs -> shfl_xor(1)
                    const float partner = __shfl_xor(val, 1);
                    float sn, cs;
                    __sincosf((float)s * invf[nt], &sn, &cs);
                    val = odd ? (val * cs + partner * sn)
                              : (val * cs - partner * sn);
                    if (z == 0) val *= 0.125f;
                    ((bf16*)out)[(size_t)z * TEN +
                                 (((size_t)(b * NH + h)) * SEQ + s) * HD + dd] = (bf16)val;
                } else {
                    ((float*)out)[(size_t)row * DM + col] = val;
                }
            }
        }
    }
}

// ---------------------------------------------------------------- flash attention (causal)
// (unchanged from round 4 — measured win: 3 blocks/CU, 2-buffer K/V, setprio.)
// grid: (bh=64, 16). qb = 15 - blockIdx.y (heavy-first). One 128-row q-block per block.
// per-tile schedule: compute(cur) -> BARRIER -> STGKV(cur, t+2) -> DRAIN(4) -> BARRIER.
__global__ __launch_bounds__(256, 3) void k_attn(const bf16* __restrict__ q,
                                                 const bf16* __restrict__ k,
                                                 const bf16* __restrict__ vt,
                                                 bf16* __restrict__ y) {
    __shared__ __align__(1024) bf16 KsF[2][4096];      // 2 x 8 KB [kv][d] swizzled
    __shared__ __align__(1024) bf16 VsF[2][4096];      // 2 x 8 KB [d][kv] swizzled
    __shared__ __align__(1024) bf16 PsF[4 * 32 * 64];  // 16 KB per-wave P scratch, swizzled
    const int t = threadIdx.x;
    const int w = t >> 6, lane = t & 63, quad = lane >> 4, l16 = lane & 15;
    const int bh = blockIdx.x;                // bh fastest => qb-blocks of one bh share an XCD
    const int qb = 15 - (int)blockIdx.y;      // heavy blocks dispatch first
    const int b = bh >> 4, h = bh & 15;

    const int srow = lane >> 3;                       // row within chunk
    const int gseg = (lane & 7) ^ srow;               // global seg fetched (de-swizzle)
    const int c0 = w, c1 = w + 4;                     // this wave's chunks

    const bf16* kbase = k  + (size_t)bh * SEQ * HD;
    const bf16* vbase = vt + (size_t)bh * HD * SEQ;
    const float NEG_INF = -__builtin_inff();

    const int koff0 = (c0 * 8 + srow) * HD + gseg * 8;
    const int koff1 = (c1 * 8 + srow) * HD + gseg * 8;
    const int voff0 = (c0 * 8 + srow) * SEQ + gseg * 8;
    const int voff1 = (c1 * 8 + srow) * SEQ + gseg * 8;

#define STGKV(buf, tt) do { \
    GLL16(kbase + (size_t)(tt) * 64 * HD + koff0, &KsF[buf][c0 * 512]); \
    GLL16(kbase + (size_t)(tt) * 64 * HD + koff1, &KsF[buf][c1 * 512]); \
    GLL16(vbase + (size_t)(tt) * 64 + voff0, &VsF[buf][c0 * 512]); \
    GLL16(vbase + (size_t)(tt) * 64 + voff1, &VsF[buf][c1 * 512]); \
} while (0)

    // Q fragments: 2 m-tiles, A-layout (issued before the staging DMAs)
    bf16x8 qf[2][2];
#pragma unroll
    for (int mt = 0; mt < 2; mt++) {
        const bf16* qrow = q + ((size_t)bh * SEQ + qb * 128 + w * 32 + mt * 16 + l16) * HD;
        qf[mt][0] = *(const bf16x8*)(qrow + quad * 8);
        qf[mt][1] = *(const bf16x8*)(qrow + 32 + quad * 8);
    }

    const int ktmax = 2 * qb + 1;
    STGKV(0, 0);
    STGKV(1, 1);

    int off_kv[4][2];
#pragma unroll
    for (int nt = 0; nt < 4; nt++) {
        const int r = nt * 16 + l16;
#pragma unroll
        for (int hh = 0; hh < 2; hh++) {
            const int sg = hh * 4 + quad;
            off_kv[nt][hh] = r * 64 + ((sg ^ (r & 7)) << 3);
        }
    }
    const bf16 *pf_p[2][2];
#pragma unroll
    for (int mt = 0; mt < 2; mt++) {
        const int r = mt * 16 + l16;
#pragma unroll
        for (int hh = 0; hh < 2; hh++) {
            const int sg = hh * 4 + quad;
            pf_p[mt][hh] = PsF + w * 2048 + r * 64 + ((sg ^ (r & 7)) << 3);
        }
    }

    f32x4 zero = {0.f, 0.f, 0.f, 0.f};
    f32x4 minus10 = {-10.f, -10.f, -10.f, -10.f};
    f32x4 acc_o[2][4];
    float l_acc[2][4];
#pragma unroll
    for (int mt = 0; mt < 2; mt++)
#pragma unroll
        for (int nt = 0; nt < 4; nt++) acc_o[mt][nt] = zero;
#pragma unroll
    for (int mt = 0; mt < 2; mt++)
#pragma unroll
        for (int rg = 0; rg < 4; rg++) l_acc[mt][rg] = 0.f;

    DRAIN(4);      // Q + tile 0 landed (tile 1 in flight)
    BARRIER();

    for (int kt = 0; kt <= ktmax; kt++) {
        const int cur = kt & 1;
        const bf16* kb_ = &KsF[0][0] + cur * 4096;
        const bf16* vb_ = &VsF[0][0] + cur * 4096;

        const int d = qb * 128 + w * 32 - kt * 64;   // wave-row offset vs kv base
        if (d > -32) {                      // else fully masked: skip (wave-uniform)
            // ---- S = Q K^T - 10
            f32x4 accs[2][4];
            __builtin_amdgcn_s_setprio(1);
#pragma unroll
            for (int nt = 0; nt < 4; nt++) {
                const bf16x8 kf0 = *(const bf16x8*)(kb_ + off_kv[nt][0]);
                const bf16x8 kf1 = *(const bf16x8*)(kb_ + off_kv[nt][1]);
#pragma unroll
                for (int mt = 0; mt < 2; mt++) {
                    f32x4 a = minus10;
                    a = MFMA16(qf[mt][0], kf0, a);
                    a = MFMA16(qf[mt][1], kf1, a);
                    accs[mt][nt] = a;
                }
            }
            __builtin_amdgcn_s_setprio(0);
            // ---- causal mask (only when the 64-kv tile straddles this wave's rows)
            if (d < 64) {
#pragma unroll
                for (int mt = 0; mt < 2; mt++) {
                    const int qr = d + mt * 16 + quad * 4;
#pragma unroll
                    for (int nt = 0; nt < 4; nt++) {
                        const int kv = nt * 16 + l16;
#pragma unroll
                        for (int rg = 0; rg < 4; rg++)
                            if (kv > qr + rg) accs[mt][nt][rg] = NEG_INF;
                    }
                }
            }
            // ---- p = exp(S-10); per-lane row-sum; P -> swizzled wave-private LDS
#pragma unroll
            for (int mt = 0; mt < 2; mt++) {
#pragma unroll
                for (int nt = 0; nt < 4; nt++) {
#pragma unroll
                    for (int rg = 0; rg < 4; rg++) {
                        const float p = __expf(accs[mt][nt][rg]);
                        l_acc[mt][rg] += p;
                        const int prow = mt * 16 + quad * 4 + rg;
                        const int psg  = (nt * 2 + (l16 >> 3)) ^ (prow & 7);
                        PsF[w * 2048 + prow * 64 + psg * 8 + (l16 & 7)] = (bf16)p;
                    }
                }
            }
            // ---- O += P V (in-order DS pipe: no barrier for wave-private P)
            bf16x8 pf[2][2];
#pragma unroll
            for (int mt = 0; mt < 2; mt++) {
                pf[mt][0] = *(const bf16x8*)pf_p[mt][0];
                pf[mt][1] = *(const bf16x8*)pf_p[mt][1];
            }
            __builtin_amdgcn_s_setprio(1);
#pragma unroll
            for (int nt = 0; nt < 4; nt++) {
                const bf16x8 vf0 = *(const bf16x8*)(vb_ + off_kv[nt][0]);
                const bf16x8 vf1 = *(const bf16x8*)(vb_ + off_kv[nt][1]);
#pragma unroll
                for (int mt = 0; mt < 2; mt++) {
                    acc_o[mt][nt] = MFMA16(pf[mt][0], vf0, acc_o[mt][nt]);
                    acc_o[mt][nt] = MFMA16(pf[mt][1], vf1, acc_o[mt][nt]);
                }
            }
            __builtin_amdgcn_s_setprio(0);
        }
        if (kt < ktmax) {
            BARRIER();                                   // buf cur's readers done
            const int ts = (kt + 2 > ktmax) ? ktmax : (kt + 2);  // clamp: restage hot tile
            STGKV(cur, ts);                              // refill freed buffer
            DRAIN(4);                                    // own S_{kt+1} complete
            BARRIER();                                   // all waves' S_{kt+1} published
        }
    }
#undef STGKV

    // ---- epilogue: reduce l over the 16 lanes holding each row, normalize, store
#pragma unroll
    for (int mt = 0; mt < 2; mt++) {
#pragma unroll
        for (int rg = 0; rg < 4; rg++) {
            float rs = l_acc[mt][rg];
            rs += __shfl_xor(rs, 1);
            rs += __shfl_xor(rs, 2);
            rs += __shfl_xor(rs, 4);
            rs += __shfl_xor(rs, 8);
            const float inv = 1.0f / rs;
            const int s = qb * 128 + w * 32 + mt * 16 + quad * 4 + rg;
#pragma unroll
            for (int nt = 0; nt < 4; nt++) {
                const float val = acc_o[mt][nt][rg] * inv;
                y[((size_t)(b * SEQ + s)) * DM + h * HD + nt * 16 + l16] = (bf16)val;
            }
        }
    }
}

// ---------------------------------------------------------------- launch
extern "C" void kernel_launch(void* const* d_in, const int* in_sizes, int n_in,
                              void* d_out, int out_size, void* d_ws, size_t ws_size,
                              hipStream_t stream) {
    const float* x  = (const float*)d_in[0];
    const float* Wq = (const float*)d_in[1];
    const float* bq = (const float*)d_in[2];
    const float* Wk = (const float*)d_in[3];
    const float* bk = (const float*)d_in[4];
    const float* Wv = (const float*)d_in[5];
    const float* bv = (const float*)d_in[6];
    const float* Wo = (const float*)d_in[7];
    const float* bo = (const float*)d_in[8];

    // Workspace layout (88 MB total).
    char* ws = (char*)d_ws;
    bf16* xb   = (bf16*)(ws);                       // 16 MB: x bf16; reused as attn out y
    bf16* wall = (bf16*)(ws + (16ull << 20));       //  8 MB: Wq^T,Wk^T,Wv^T,Wo^T bf16
    bf16* qb   = (bf16*)(ws + (24ull << 20));       // 16 MB (q at +0, k at +TEN)
    bf16* kb   = (bf16*)(ws + (40ull << 20));       // 16 MB
    bf16* vtb  = (bf16*)(ws + (72ull << 20));       // 16 MB: V^T [B,H,D,S] (written by k_gemm<0> z=2)
    bf16* wot  = wall + 3ull * DM * DM;

    k_prep<<<dim3(16, 16, 5), 256, 0, stream>>>(x, Wq, Wk, Wv, Wo, wall, xb);
    k_gemm<0><<<dim3(32, 24), 512, 0, stream>>>(xb, wall, bq, bk, bv, vtb, qb);
    k_attn<<<dim3(64, 16), 256, 0, stream>>>(qb, kb, vtb, xb);
    k_gemm<1><<<dim3(32, 8), 512, 0, stream>>>(xb, wot, bo, bo, bo, vtb, d_out);
}